// Round 4
// baseline (433.854 us; speedup 1.0000x reference)
//
#include <hip/hip_runtime.h>
#include <stdint.h>

typedef unsigned short u16;
typedef __bf16 bf16x8 __attribute__((ext_vector_type(8)));
typedef float f32x4 __attribute__((ext_vector_type(4)));

// ---------- helpers ----------
__device__ __forceinline__ u16 f2b(float f) {
  union { float f; uint32_t u; } v; v.f = f;
  uint32_t r = v.u + 0x7fffu + ((v.u >> 16) & 1u);
  return (u16)(r >> 16);
}
__device__ __forceinline__ float b2f(u16 b) {
  union { float f; uint32_t u; } v; v.u = ((uint32_t)b) << 16;
  return v.f;
}
// async 16B/lane global->LDS (dest = uniform base + lane*16)
__device__ __forceinline__ void g2l16(const void* g, void* l) {
  __builtin_amdgcn_global_load_lds(
      (const __attribute__((address_space(1))) void*)g,
      (__attribute__((address_space(3))) void*)l, 16, 0, 0);
}

#define N_SAMP 128
#define OPAD   224
#define ROWS   (N_SAMP * OPAD)   // 28672

// ---------- K0a: weight repack ----------
__global__ __launch_bounds__(256) void prep_weights(
    const float* __restrict__ conv_w, const float* __restrict__ hp_w0,
    const float* __restrict__ gt_w0, const float* __restrict__ gt_w1,
    u16* __restrict__ W2, u16* __restrict__ hp_w0t,
    u16* __restrict__ gt_w0t, u16* __restrict__ gt_w1t) {
  int idx = blockIdx.x * 256 + threadIdx.x;
  const int nW2 = 9 * 128 * 1024;
  const int nHP = 256 * 288;
  const int nGT0 = 256 * 288;
  const int nGT1 = 256 * 256;
  if (idx < nW2) {
    int s = idx / 131072; int r = idx & 131071;
    int cf = r >> 10; int cin = r & 1023;
    W2[idx] = f2b(conv_w[(cf * 1024 + cin) * 9 + s]);
    return;
  }
  idx -= nW2;
  if (idx < nHP) {
    int nn = idx / 288, kk = idx % 288;
    hp_w0t[nn * 288 + kk] = (kk < 258) ? f2b(hp_w0[kk * 256 + nn]) : (u16)0;
    return;
  }
  idx -= nHP;
  if (idx < nGT0) {
    int nn = idx / 288, kk = idx % 288;
    gt_w0t[nn * 288 + kk] = (kk < 258) ? f2b(gt_w0[kk * 256 + nn]) : (u16)0;
    return;
  }
  idx -= nGT0;
  if (idx < nGT1) {
    int nn = idx >> 8, kk = idx & 255;
    gt_w1t[nn * 256 + kk] = f2b(gt_w1[kk * 256 + nn]);
  }
}

// ---------- K0b: image -> imgT[n][256 sp (16x16 zero-bordered)][1024 cin] bf16 ----------
__global__ __launch_bounds__(256) void prep_img(const float* __restrict__ image,
                                                u16* __restrict__ imgT) {
  __shared__ float t[64][197];
  int n = blockIdx.x >> 4;
  int cin0 = (blockIdx.x & 15) * 64;
  const float* src = image + ((size_t)n * 1024 + cin0) * 196;
  for (int e = threadIdx.x; e < 64 * 196; e += 256) {
    int c = e / 196, sp = e % 196;
    t[c][sp] = src[c * 196 + sp];
  }
  __syncthreads();
  int w = threadIdx.x >> 6, lane = threadIdx.x & 63;
  for (int i = 0; i < 64; ++i) {
    int spg = i * 4 + w;
    int gy = spg >> 4, gx = spg & 15;
    float v = 0.f;
    if (gy >= 1 && gy <= 14 && gx >= 1 && gx <= 14) v = t[lane][(gy - 1) * 14 + (gx - 1)];
    imgT[(((size_t)(n * 256 + spg)) << 10) + cin0 + lane] = f2b(v);
  }
}

// ---------- K2: qeb cols 128..287 (+ zero padded rows' cols 0..127) ----------
__global__ __launch_bounds__(256) void fill_qe(const float* __restrict__ code,
                                               u16* __restrict__ qeb) {
  int base = blockIdx.x * 8;
  for (int rr = 0; rr < 8; ++rr) {
    int r = base + rr;
    int n = r / 224, o = r % 224;
    int y = o / 14, x = o % 14;
    bool valid = o < 196;
    u16* row = qeb + (size_t)r * 288;
    for (int c = threadIdx.x; c < 288; c += 256) {
      u16 v;
      if (c < 128) { if (valid) continue; v = 0; }
      else if (c == 128) v = valid ? f2b(-1.f + 2.f * y / 13.f) : (u16)0;
      else if (c == 129) v = valid ? f2b(-1.f + 2.f * x / 13.f) : (u16)0;
      else if (c < 258) v = valid ? f2b(code[n * 128 + (c - 130)]) : (u16)0;
      else v = 0;
      row[c] = v;
    }
  }
}

// ---------- K1: conv as implicit GEMM with 9-tap A-reuse ----------
// Block = full n: M=224 (2 wm x 112), N=128 (2 wn x 64), K split 4 over cin.
// grid 512 = 128 n x 4 ks = 2 blocks/CU. Per cin-block of 32:
//   A = full 16x16 spatial grid x 32 cin staged ONCE (16 KB), reused by all 9 taps
//   (tap = pure LDS row shift dy*16+dx). B (128 cols x 32 cin) staged per tap, ring-4.
// Fully static tap schedule (no div/branches); ONE barrier + ONE sched_barrier per step;
// counted vmcnt (4 steady / 8 around A-prefetch), never 0 mid-loop. No walls around MFMA:
// compiler emits fine-grained lgkmcnt so reads/MFMA/next-stage interleave.
// Ordering audit: stage-writes of slot k (step s) vs last reads of k (step s-2, after
// barrier s-2): ordered via barrier(s-1) + the sched_barrier following it. A-buf writes
// (cb,7) vs reads (cb-1,8): ordered via barrier(cb,0)..(cb,6)+SB. vmcnt asm has "memory"
// clobber so no LDS read hoists above it.
__global__ __launch_bounds__(256) void conv_gemm(
    const u16* __restrict__ imgT, const u16* __restrict__ W2,
    float* __restrict__ convAcc) {
  __shared__ __align__(16) u16 lA[2][256 * 32];   // 2 x 16 KB, dbuf per cin-block
  __shared__ __align__(16) u16 lB[4][128 * 32];   // 4 x 8 KB ring, per (cin-block, tap)
  int tid = threadIdx.x, lane = tid & 63, w = tid >> 6;
  int wg = blockIdx.x;
  int xcd = wg & 7;
  int ks = xcd >> 1;                       // K-split id 0..3 (cin slice of 256)
  int n = ((wg >> 3) << 1) | (xcd & 1);
  int kbase = ks << 3;                     // base cin-block (cb32 units, 8 per ks)
  size_t nBase = (size_t)n << 8;
  int wm = w >> 1, wn = w & 1;             // wave tile: rows wm*112.., cols wn*64..
  int rowIn = lane >> 2;                   // staging: 16 rows/instr, 4 lanes (64B) per row
  int swz = (((lane & 3) ^ ((rowIn >> 1) & 3)) << 3);  // pre-swizzled source chunk (elems)

  int l = lane & 15, q = lane >> 4;        // MFMA: row/col sel l, k-chunk q

  // per-lane A row base for each m-tile (grid position of output o); invalid -> 0
  int posB[7];
#pragma unroll
  for (int mt = 0; mt < 7; ++mt) {
    int o = wm * 112 + mt * 16 + l;
    int y = o / 14, x = o - y * 14;
    posB[mt] = (o < 196) ? (y * 16 + x) : 0;
  }

  f32x4 acc[7][4];
#pragma unroll
  for (int mt = 0; mt < 7; ++mt)
#pragma unroll
    for (int j = 0; j < 4; ++j) acc[mt][j] = (f32x4){0.f, 0.f, 0.f, 0.f};

  // A stage: 4 instrs/wave (wave w -> grid rows w*64 + ii*16), cbl = local cin-block
  auto STAGE_A = [&](int buf, int cbl) {
    int k0 = (kbase + cbl) << 5;
#pragma unroll
    for (int ii = 0; ii < 4; ++ii) {
      int r = w * 64 + ii * 16;
      g2l16(imgT + ((nBase + (size_t)(r + rowIn)) << 10) + k0 + swz,
            &lA[buf][r * 32]);
    }
  };
  // B stage: 2 instrs/wave (wave w -> cols w*32 + ii*16), tap tp of cin-block cbl
  auto STAGE_B = [&](int slot, int cbl, int tp) {
    int k0 = (kbase + cbl) << 5;
    const u16* Ws = W2 + (((size_t)tp * 128) << 10);
#pragma unroll
    for (int ii = 0; ii < 2; ++ii) {
      int c = w * 32 + ii * 16;
      g2l16(Ws + ((size_t)(c + rowIn) << 10) + k0 + swz, &lB[slot][c * 32]);
    }
  };

  auto COMPUTE = [&](int abuf, int slot, int tOff) {
    const char* aS = (const char*)lA[abuf];
    const char* bS = (const char*)lB[slot];
    bf16x8 af[7], bf[4];
#pragma unroll
    for (int mt = 0; mt < 7; ++mt) {
      int r = posB[mt] + tOff;
      af[mt] = *(const bf16x8*)(aS + (r << 6) + (((q ^ (r >> 1)) & 3) << 4));
    }
#pragma unroll
    for (int j = 0; j < 4; ++j) {
      int rc = wn * 64 + j * 16 + l;
      bf[j] = *(const bf16x8*)(bS + (rc << 6) + (((q ^ (rc >> 1)) & 3) << 4));
    }
#pragma unroll
    for (int mt = 0; mt < 7; ++mt)
#pragma unroll
      for (int j = 0; j < 4; ++j)
        acc[mt][j] = __builtin_amdgcn_mfma_f32_16x16x32_bf16(af[mt], bf[j], acc[mt][j], 0, 0, 0);
  };

  constexpr int TOFF[9] = {0, 1, 2, 16, 17, 18, 32, 33, 34};

  // prologue: A(cb0):4 + B(0):2 + B(1):2 = 8 outstanding per wave
  STAGE_A(0, 0);
  STAGE_B(0, 0, 0);
  STAGE_B(1, 0, 1);

#pragma unroll 1
  for (int cb = 0; cb < 7; ++cb) {
#pragma unroll
    for (int tap = 0; tap < 9; ++tap) {
      if (tap < 7) STAGE_B((cb + tap + 2) & 3, cb, tap + 2);
      else         STAGE_B((cb + tap + 2) & 3, cb + 1, tap - 7);
      if (tap == 7) STAGE_A((cb + 1) & 1, cb + 1);
      // ledger: steady outstanding = B(s+1),B(s+2) = 4; around A-prefetch +4
      if (tap < 7) asm volatile("s_waitcnt vmcnt(4)" ::: "memory");
      else         asm volatile("s_waitcnt vmcnt(8)" ::: "memory");
      __builtin_amdgcn_s_barrier();
      __builtin_amdgcn_sched_barrier(0);
      COMPUTE(cb & 1, (cb + tap) & 3, TOFF[tap]);
    }
  }
  // cb == 7 (tail: no A-prefetch; last two steps stage nothing)
#pragma unroll
  for (int tap = 0; tap < 9; ++tap) {
    if (tap < 7) {
      STAGE_B((7 + tap + 2) & 3, 7, tap + 2);
      asm volatile("s_waitcnt vmcnt(4)" ::: "memory");
    } else if (tap == 7) {
      asm volatile("s_waitcnt vmcnt(2)" ::: "memory");
    } else {
      asm volatile("s_waitcnt vmcnt(0)" ::: "memory");
    }
    __builtin_amdgcn_s_barrier();
    __builtin_amdgcn_sched_barrier(0);
    COMPUTE(1, (7 + tap) & 3, TOFF[tap]);
  }

  // epilogue: atomic fp32 accumulate of the K-slice partial
#pragma unroll
  for (int mt = 0; mt < 7; ++mt) {
    int o = wm * 112 + mt * 16 + q * 4;
#pragma unroll
    for (int j = 0; j < 4; ++j) {
      int col = wn * 64 + j * 16 + l;
#pragma unroll
      for (int r4 = 0; r4 < 4; ++r4) {
        if (o + r4 < 196)
          atomicAdd(convAcc + (size_t)(n * 224 + o + r4) * 128 + col, acc[mt][j][r4]);
      }
    }
  }
}

// ---------- K1b: convAcc + bias -> qeb bf16 cols 0..127 ----------
__global__ __launch_bounds__(256) void conv_fix(
    const float* __restrict__ convAcc, const float* __restrict__ conv_b,
    u16* __restrict__ qeb) {
  int idx = blockIdx.x * 256 + threadIdx.x;   // 128*196*32
  int row196 = idx >> 5;
  int c0 = (idx & 31) << 2;
  int n = row196 / 196, o = row196 - n * 196;
  size_t row = (size_t)(n * 224 + o);
  const float4 v = *(const float4*)(convAcc + (row << 7) + c0);
  const float4 b = *(const float4*)(conv_b + c0);
  ushort4 pk;
  pk.x = f2b(v.x + b.x); pk.y = f2b(v.y + b.y);
  pk.z = f2b(v.z + b.z); pk.w = f2b(v.w + b.w);
  *(ushort4*)(qeb + row * 288 + c0) = pk;
}

// ---------- generic GEMM skeleton: C[28672, 256] = A[28672,KP]bf16 * Bt[256,KP]^T ----------
// Double-buffered counted-vmcnt pipeline; 4 global_load_lds per wave per K-step.
// A staging padded to 128 rows (row group 7 garbage, never read by MFMA).
template <int MODE, int KP, int KC>
__global__ __launch_bounds__(256) void gemm_kernel(
    const u16* __restrict__ A, const u16* __restrict__ Bt,
    const float* __restrict__ bias, const float* __restrict__ vec,
    float* __restrict__ outF, u16* __restrict__ outB) {
  __shared__ __align__(16) u16 lA[2][128 * 32];
  __shared__ __align__(16) u16 lB[2][128 * 32];
  int tid = threadIdx.x, lane = tid & 63, w = tid >> 6;
  int bx = blockIdx.x, by = blockIdx.y;
  int r0 = bx * 112;
  int cBase = by * 128;
  int kb = (((lane & 3) ^ ((lane >> 3) & 3)) << 3);   // XOR-swizzled source chunk
  int rA0 = r0 + w * 16 + (lane >> 2);
  int rA1 = r0 + (w + 4) * 16 + (lane >> 2);          // group 7 (rows 112..127) = pad
  const u16* gA0 = A + (size_t)rA0 * KP + kb;
  const u16* gA1 = A + (size_t)rA1 * KP + kb;
  int cB0 = cBase + w * 16 + (lane >> 2);
  int cB1 = cBase + (w + 4) * 16 + (lane >> 2);
  const u16* gB0 = Bt + (size_t)cB0 * KP + kb;
  const u16* gB1 = Bt + (size_t)cB1 * KP + kb;

  f32x4 acc[7][2];
#pragma unroll
  for (int mt = 0; mt < 7; ++mt)
#pragma unroll
    for (int j = 0; j < 2; ++j) acc[mt][j] = (f32x4){0.f, 0.f, 0.f, 0.f};
  int colW = w * 32;
  int l = lane & 15, q = lane >> 4;
  int co = ((q ^ ((l >> 1) & 3)) << 3);

  auto STAGE = [&](int buf, int cb) {
    g2l16(gA0 + cb * 32, &lA[buf][w * 512]);
    g2l16(gA1 + cb * 32, &lA[buf][(w + 4) * 512]);
    g2l16(gB0 + cb * 32, &lB[buf][w * 512]);
    g2l16(gB1 + cb * 32, &lB[buf][(w + 4) * 512]);
  };

  auto COMPUTE = [&](int cur) {
    bf16x8 af[7];
#pragma unroll
    for (int mt = 0; mt < 7; ++mt)
      af[mt] = *(const bf16x8*)&lA[cur][(mt * 16 + l) * 32 + co];
#pragma unroll
    for (int j = 0; j < 2; ++j) {
      bf16x8 bfr = *(const bf16x8*)&lB[cur][(colW + j * 16 + l) * 32 + co];
#pragma unroll
      for (int mt = 0; mt < 7; ++mt)
        acc[mt][j] = __builtin_amdgcn_mfma_f32_16x16x32_bf16(af[mt], bfr, acc[mt][j], 0, 0, 0);
    }
  };

  STAGE(0, 0);
#pragma unroll
  for (int it = 0; it < KC - 1; ++it) {
    STAGE((it & 1) ^ 1, it + 1);
    asm volatile("s_waitcnt vmcnt(4)" ::: "memory");   // prev step's 4 loads done; 4 in flight
    __builtin_amdgcn_s_barrier();
    __builtin_amdgcn_sched_barrier(0);
    COMPUTE(it & 1);
    __builtin_amdgcn_s_barrier();                      // all reads done before next STAGE overwrites
    __builtin_amdgcn_sched_barrier(0);
  }
  asm volatile("s_waitcnt vmcnt(0)" ::: "memory");
  __builtin_amdgcn_s_barrier();
  __builtin_amdgcn_sched_barrier(0);
  COMPUTE((KC - 1) & 1);

  int q4 = lane >> 4, c = lane & 15;
  if (MODE == 0) {
    float attp[7][4];
#pragma unroll
    for (int mt = 0; mt < 7; ++mt)
#pragma unroll
      for (int r = 0; r < 4; ++r) attp[mt][r] = 0.f;
#pragma unroll
    for (int j = 0; j < 2; ++j) {
      int col = cBase + colW + j * 16 + c;
      float b0 = bias[col], w1 = vec[col];
#pragma unroll
      for (int mt = 0; mt < 7; ++mt)
#pragma unroll
        for (int r = 0; r < 4; ++r) {
          float v = fmaxf(acc[mt][j][r] + b0, 0.f);
          attp[mt][r] += v * w1;
        }
    }
#pragma unroll
    for (int mt = 0; mt < 7; ++mt)
#pragma unroll
      for (int r = 0; r < 4; ++r) {
        float p = attp[mt][r];
        p += __shfl_xor(p, 1, 64);
        p += __shfl_xor(p, 2, 64);
        p += __shfl_xor(p, 4, 64);
        p += __shfl_xor(p, 8, 64);
        if (c == 0) atomicAdd(&outF[r0 + mt * 16 + q4 * 4 + r], p);
      }
  } else if (MODE == 1) {
    int n = bx >> 1;
#pragma unroll
    for (int mt = 0; mt < 7; ++mt)
#pragma unroll
      for (int j = 0; j < 2; ++j) {
        int col = cBase + colW + j * 16 + c;
        float b = bias[n * 256 + col];
#pragma unroll
        for (int r = 0; r < 4; ++r) {
          int row = r0 + mt * 16 + q4 * 4 + r;
          outB[(size_t)row * 256 + col] = f2b(fmaxf(acc[mt][j][r] + b, 0.f));
        }
      }
  } else {
    int n = bx >> 1;
    int ob = (bx & 1) * 112;
#pragma unroll
    for (int j = 0; j < 2; ++j) {
      int col = cBase + colW + j * 16 + c;
      float b = bias[col];
      float sum = 0.f;
#pragma unroll
      for (int mt = 0; mt < 7; ++mt)
#pragma unroll
        for (int r = 0; r < 4; ++r) {
          int o = ob + mt * 16 + q4 * 4 + r;
          if (o < 196) sum += fmaxf(acc[mt][j][r] + b, 0.f);
        }
      sum += __shfl_xor(sum, 16, 64);
      sum += __shfl_xor(sum, 32, 64);
      if (q4 == 0) atomicAdd(&outF[n * 256 + col], sum);
    }
  }
}

// ---------- K5: softmax over objects, soft-select, per-n bias2 ----------
__global__ __launch_bounds__(256) void sel_kernel(
    const float* __restrict__ att, const u16* __restrict__ qeb,
    const float* __restrict__ gt_w0, const float* __restrict__ gt_b0,
    float* __restrict__ bias2) {
  int n = blockIdx.x, t = threadIdx.x;
  int w = t >> 6, lane = t & 63;
  __shared__ u16 sq[196][130];
  __shared__ float sm[196];
  __shared__ float sel[130];
  __shared__ float red[8];
  // cooperative stage of qeb[n, 0:196, 0:130]
  const u16* base = qeb + (size_t)n * 224 * 288;
  for (int o = w; o < 196; o += 4) {
    const u16* rowp = base + (size_t)o * 288;
    for (int c = lane; c < 130; c += 64) sq[o][c] = rowp[c];
  }
  float a = (t < 196) ? att[n * 224 + t] : -1e30f;
  float m = a;
  for (int mask = 1; mask < 64; mask <<= 1) m = fmaxf(m, __shfl_xor(m, mask, 64));
  if (lane == 0) red[w] = m;
  __syncthreads();
  float M = fmaxf(fmaxf(red[0], red[1]), fmaxf(red[2], red[3]));
  float e = (t < 196) ? expf(a - M) : 0.f;
  float sAcc = e;
  for (int mask = 1; mask < 64; mask <<= 1) sAcc += __shfl_xor(sAcc, mask, 64);
  if (lane == 0) red[4 + w] = sAcc;
  __syncthreads();
  float S = red[4] + red[5] + red[6] + red[7];
  if (t < 196) sm[t] = e / S;
  __syncthreads();
  if (t < 130) {
    float acc = 0.f;
    for (int o = 0; o < 196; ++o) acc += sm[o] * b2f(sq[o][t]);
    sel[t] = acc;
  }
  __syncthreads();
  float acc2 = gt_b0[t];
  for (int d = 0; d < 130; ++d) acc2 += sel[d] * gt_w0[(258 + d) * 256 + t];
  bias2[n * 256 + t] = acc2;
}

// ---------- K8: f_phi ----------
__global__ __launch_bounds__(256) void fphi(
    const float* __restrict__ relations, const float* __restrict__ fp_w0,
    const float* __restrict__ fp_b0, const float* __restrict__ fp_w1,
    const float* __restrict__ fp_b1, float* __restrict__ out) {
  int n = blockIdx.x, t = threadIdx.x;
  __shared__ float rel[256];
  __shared__ float f[256];
  rel[t] = relations[n * 256 + t];
  __syncthreads();
  float acc = fp_b0[t];
  for (int k = 0; k < 256; ++k) acc += rel[k] * fp_w0[k * 256 + t];
  f[t] = fmaxf(acc, 0.f);
  __syncthreads();
  if (t < 32) {
    float o = fp_b1[0];
    for (int k = 0; k < 256; ++k) o += f[k] * fp_w1[k * 32 + t];
    out[n * 32 + t] = o;
  }
}

extern "C" void kernel_launch(void* const* d_in, const int* in_sizes, int n_in,
                              void* d_out, int out_size, void* d_ws, size_t ws_size,
                              hipStream_t stream) {
  const float* image = (const float*)d_in[0];
  const float* code = (const float*)d_in[1];
  const float* conv_w = (const float*)d_in[2];
  const float* conv_b = (const float*)d_in[3];
  const float* hp_w0 = (const float*)d_in[4];
  const float* hp_b0 = (const float*)d_in[5];
  const float* hp_w1 = (const float*)d_in[6];
  /* hp_b1: softmax shift-invariant, dropped */
  const float* gt_w0 = (const float*)d_in[8];
  const float* gt_b0 = (const float*)d_in[9];
  const float* gt_w1 = (const float*)d_in[10];
  const float* gt_b1 = (const float*)d_in[11];
  const float* fp_w0 = (const float*)d_in[12];
  const float* fp_b0 = (const float*)d_in[13];
  const float* fp_w1 = (const float*)d_in[14];
  const float* fp_b1 = (const float*)d_in[15];
  float* out = (float*)d_out;

  char* p = (char*)d_ws;
  u16* imgT = (u16*)p;   p += (size_t)128 * 256 * 1024 * 2;   // 67.1 MB
  u16* W2 = (u16*)p;     p += (size_t)9 * 128 * 1024 * 2;     // 2.36 MB
  u16* qeb = (u16*)p;    p += (size_t)ROWS * 288 * 2;         // 16.5 MB
  u16* hp_w0t = (u16*)p; p += (size_t)256 * 288 * 2;
  u16* gt_w0t = (u16*)p; p += (size_t)256 * 288 * 2;
  u16* gt_w1t = (u16*)p; p += (size_t)256 * 256 * 2;
  float* att = (float*)p;   p += (size_t)ROWS * 4;
  float* bias2 = (float*)p; p += (size_t)128 * 256 * 4;
  float* convAcc = (float*)p; p += (size_t)ROWS * 128 * 4;    // 14.7 MB; reused as g1
  float* relations = (float*)p; p += (size_t)128 * 256 * 4;
  u16* g1 = (u16*)convAcc;   // alias: convAcc dead after conv_fix, g1 born at MODE1

  hipMemsetAsync(att, 0, (size_t)ROWS * 4, stream);
  hipMemsetAsync(relations, 0, (size_t)128 * 256 * 4, stream);
  hipMemsetAsync(convAcc, 0, (size_t)ROWS * 128 * 4, stream);

  prep_weights<<<5440, 256, 0, stream>>>(conv_w, hp_w0, gt_w0, gt_w1, W2, hp_w0t, gt_w0t, gt_w1t);
  prep_img<<<2048, 256, 0, stream>>>(image, imgT);
  fill_qe<<<ROWS / 8, 256, 0, stream>>>(code, qeb);
  conv_gemm<<<512, 256, 0, stream>>>(imgT, W2, convAcc);
  conv_fix<<<3136, 256, 0, stream>>>(convAcc, conv_b, qeb);
  gemm_kernel<0, 288, 9><<<dim3(256, 2), 256, 0, stream>>>(qeb, hp_w0t, hp_b0, hp_w1, att, nullptr);
  sel_kernel<<<128, 256, 0, stream>>>(att, qeb, gt_w0, gt_b0, bias2);
  gemm_kernel<1, 288, 9><<<dim3(256, 2), 256, 0, stream>>>(qeb, gt_w0t, bias2, nullptr, nullptr, g1);
  gemm_kernel<2, 256, 8><<<dim3(256, 2), 256, 0, stream>>>(g1, gt_w1t, gt_b1, nullptr, relations, nullptr);
  fphi<<<128, 256, 0, stream>>>(relations, fp_w0, fp_b0, fp_w1, fp_b1, out);
}

// Round 5
// 397.035 us; speedup vs baseline: 1.0927x; 1.0927x over previous
//
#include <hip/hip_runtime.h>
#include <stdint.h>

typedef unsigned short u16;
typedef __bf16 bf16x8 __attribute__((ext_vector_type(8)));
typedef float f32x4 __attribute__((ext_vector_type(4)));

// ---------- helpers ----------
__device__ __forceinline__ u16 f2b(float f) {
  union { float f; uint32_t u; } v; v.f = f;
  uint32_t r = v.u + 0x7fffu + ((v.u >> 16) & 1u);
  return (u16)(r >> 16);
}
__device__ __forceinline__ float b2f(u16 b) {
  union { float f; uint32_t u; } v; v.u = ((uint32_t)b) << 16;
  return v.f;
}
// async 16B/lane global->LDS (dest = uniform base + lane*16)
__device__ __forceinline__ void g2l16(const void* g, void* l) {
  __builtin_amdgcn_global_load_lds(
      (const __attribute__((address_space(1))) void*)g,
      (__attribute__((address_space(3))) void*)l, 16, 0, 0);
}

#define N_SAMP 128
#define OPAD   224
#define ROWS   (N_SAMP * OPAD)   // 28672
#define KQ     160               // qeb K: 128 conv + 2 coords + 30 zero pad

// ---------- K0a: weight repack + per-n code-bias (code folded out of K) ----------
__global__ __launch_bounds__(256) void prep_weights(
    const float* __restrict__ conv_w, const float* __restrict__ hp_w0,
    const float* __restrict__ gt_w0, const float* __restrict__ gt_w1,
    const float* __restrict__ hp_b0, const float* __restrict__ code,
    u16* __restrict__ W2, u16* __restrict__ hp_w0t,
    u16* __restrict__ gt_w0t, u16* __restrict__ gt_w1t,
    float* __restrict__ biasHP) {
  int idx = blockIdx.x * 256 + threadIdx.x;
  const int nW2 = 9 * 128 * 1024;
  const int nHP = 256 * KQ;
  const int nGT0 = 256 * KQ;
  const int nGT1 = 256 * 256;
  if (idx < nW2) {
    int s = idx / 131072; int r = idx & 131071;
    int cf = r >> 10; int cin = r & 1023;
    W2[idx] = f2b(conv_w[(cf * 1024 + cin) * 9 + s]);
    return;
  }
  idx -= nW2;
  if (idx < nHP) {
    int nn = idx / KQ, kk = idx % KQ;
    hp_w0t[nn * KQ + kk] = (kk < 130) ? f2b(hp_w0[kk * 256 + nn]) : (u16)0;
    return;
  }
  idx -= nHP;
  if (idx < nGT0) {
    int nn = idx / KQ, kk = idx % KQ;
    gt_w0t[nn * KQ + kk] = (kk < 130) ? f2b(gt_w0[kk * 256 + nn]) : (u16)0;
    return;
  }
  idx -= nGT0;
  if (idx < nGT1) {
    int nn = idx >> 8, kk = idx & 255;
    gt_w1t[nn * 256 + kk] = f2b(gt_w1[kk * 256 + nn]);
    return;
  }
  idx -= nGT1;
  // biasHP[n][t] = hp_b0[t] + sum_d code[n,d] * hp_w0[130+d, t]   (128*256 threads)
  {
    int n = idx >> 8, t = idx & 255;
    float acc = hp_b0[t];
    for (int d = 0; d < 128; ++d)
      acc += code[n * 128 + d] * hp_w0[(130 + d) * 256 + t];
    biasHP[n * 256 + t] = acc;
  }
}

// ---------- K0b: image -> imgT[n][256 sp (16x16 zero-bordered)][1024 cin] bf16 ----------
__global__ __launch_bounds__(256) void prep_img(const float* __restrict__ image,
                                                u16* __restrict__ imgT) {
  __shared__ float t[64][197];
  int n = blockIdx.x >> 4;
  int cin0 = (blockIdx.x & 15) * 64;
  const float* src = image + ((size_t)n * 1024 + cin0) * 196;
  for (int e = threadIdx.x; e < 64 * 196; e += 256) {
    int c = e / 196, sp = e % 196;
    t[c][sp] = src[c * 196 + sp];
  }
  __syncthreads();
  int w = threadIdx.x >> 6, lane = threadIdx.x & 63;
  for (int i = 0; i < 64; ++i) {
    int spg = i * 4 + w;
    int gy = spg >> 4, gx = spg & 15;
    float v = 0.f;
    if (gy >= 1 && gy <= 14 && gx >= 1 && gx <= 14) v = t[lane][(gy - 1) * 14 + (gx - 1)];
    imgT[(((size_t)(n * 256 + spg)) << 10) + cin0 + lane] = f2b(v);
  }
}

// ---------- K2: qeb coord cols 128..159 + zero pad rows (KQ=160 layout) ----------
// range 1: ROWS*8 ushort4-quads covering cols 128..159 of every row
// range 2: 3584 pad rows x 32 quads covering cols 0..127
__global__ __launch_bounds__(256) void fill_qe(u16* __restrict__ qeb) {
  int idx = blockIdx.x * 256 + threadIdx.x;
  if (idx < ROWS * 8) {
    int row = idx >> 3, qd = idx & 7;
    int o = row % 224;
    ushort4 v = {0, 0, 0, 0};
    if (o < 196 && qd == 0) {
      int y = o / 14, x = o % 14;
      v.x = f2b(-1.f + 2.f * y / 13.f);
      v.y = f2b(-1.f + 2.f * x / 13.f);
    }
    *(ushort4*)(qeb + (size_t)row * KQ + 128 + qd * 4) = v;
    return;
  }
  idx -= ROWS * 8;   // 3584 * 32
  int pr = idx >> 5, qd = idx & 31;
  int row = (pr / 28) * 224 + 196 + (pr % 28);
  *(ushort4*)(qeb + (size_t)row * KQ + qd * 4) = (ushort4){0, 0, 0, 0};
}

// ---------- K1: conv as implicit GEMM, split-K x3 (round-0 proven structure) ----------
// grid 768 = 8 xcd * (16 ngrp * 2 ohalf * 3 kslice); BK=64; swizzled LDS.
__global__ __launch_bounds__(256) void conv_gemm(
    const u16* __restrict__ imgT, const u16* __restrict__ W2,
    float* __restrict__ convAcc) {
  __shared__ __align__(16) u16 lA[112 * 64];
  __shared__ __align__(16) u16 lB[128 * 64];
  int tid = threadIdx.x, lane = tid & 63, w = tid >> 6;
  int wg = blockIdx.x;
  int xcd = wg & 7, grp = wg >> 3;          // same-n blocks land on same XCD
  int n = ((grp / 6) << 3) | xcd;
  int r6 = grp % 6;
  int oh = r6 / 3, ks = r6 % 3;
  int oBase = oh * 112;
  size_t nBase = (size_t)n << 8;
  int rowIn = lane >> 3;                    // row within 8-row staging instr
  int cA = ((lane & 7) ^ rowIn) << 3;       // XOR-swizzled chunk offset (elems)

  // A-row spatial precompute for staging instrs t = w + 4*ii
  int yxA[4];
  for (int ii = 0; ii < 4; ++ii) {
    int t = w + ii * 4;
    int o = oBase + t * 8 + rowIn;
    bool valid = o < 196;
    int y = o / 14, x = o - y * 14;
    yxA[ii] = valid ? (y * 16 + x) : 0;    // invalid rows read border zeros / garbage; outputs discarded
  }

  f32x4 acc[7][2];
#pragma unroll
  for (int mt = 0; mt < 7; ++mt)
#pragma unroll
    for (int j = 0; j < 2; ++j) acc[mt][j] = (f32x4){0.f, 0.f, 0.f, 0.f};

  int l = lane & 15, q = lane >> 4;
  for (int si = 0; si < 3; ++si) {
    int s = ks * 3 + si;
    int off = (s / 3) * 16 + (s % 3);
    const u16* Ws = W2 + ((size_t)(s * 128) << 10);
    for (int cb = 0; cb < 16; ++cb) {
      int k0 = cb << 6;
      __syncthreads();
      // stage A: 14 instrs (waves 0,1: 4 each; waves 2,3: 3 each)
      g2l16(imgT + ((nBase + (size_t)(yxA[0] + off)) << 10) + k0 + cA, &lA[(w) * 512]);
      g2l16(imgT + ((nBase + (size_t)(yxA[1] + off)) << 10) + k0 + cA, &lA[(w + 4) * 512]);
      g2l16(imgT + ((nBase + (size_t)(yxA[2] + off)) << 10) + k0 + cA, &lA[(w + 8) * 512]);
      if (w < 2)
        g2l16(imgT + ((nBase + (size_t)(yxA[3] + off)) << 10) + k0 + cA, &lA[(w + 12) * 512]);
      // stage B: 16 instrs (4 per wave)
#pragma unroll
      for (int ii = 0; ii < 4; ++ii) {
        int t = w + ii * 4;
        g2l16(Ws + ((size_t)(t * 8 + rowIn) << 10) + k0 + cA, &lB[t * 512]);
      }
      __syncthreads();
#pragma unroll
      for (int kk = 0; kk < 2; ++kk) {
        int co = ((((kk << 2) | q) ^ (l & 7)) << 3);
        bf16x8 af[7];
#pragma unroll
        for (int mt = 0; mt < 7; ++mt)
          af[mt] = *(const bf16x8*)&lA[(mt * 16 + l) * 64 + co];
#pragma unroll
        for (int jj = 0; jj < 2; ++jj) {
          bf16x8 bb = *(const bf16x8*)&lB[(w * 32 + jj * 16 + l) * 64 + co];
#pragma unroll
          for (int mt = 0; mt < 7; ++mt)
            acc[mt][jj] = __builtin_amdgcn_mfma_f32_16x16x32_bf16(af[mt], bb, acc[mt][jj], 0, 0, 0);
        }
      }
    }
  }
  // epilogue: atomic fp32 accumulate of the K-slice partial
#pragma unroll
  for (int mt = 0; mt < 7; ++mt) {
    int o = oBase + mt * 16 + q * 4;
#pragma unroll
    for (int r4 = 0; r4 < 4; ++r4) {
      if (o + r4 < 196) {
        float* dst = convAcc + (size_t)(n * 224 + o + r4) * 128 + w * 32 + l;
        atomicAdd(dst, acc[mt][0][r4]);
        atomicAdd(dst + 16, acc[mt][1][r4]);
      }
    }
  }
}

// ---------- K1b: convAcc + bias -> qeb bf16 cols 0..127 ----------
__global__ __launch_bounds__(256) void conv_fix(
    const float* __restrict__ convAcc, const float* __restrict__ conv_b,
    u16* __restrict__ qeb) {
  int idx = blockIdx.x * 256 + threadIdx.x;   // 128*196*32
  int row196 = idx >> 5;
  int c0 = (idx & 31) << 2;
  int n = row196 / 196, o = row196 - n * 196;
  size_t row = (size_t)(n * 224 + o);
  const float4 v = *(const float4*)(convAcc + (row << 7) + c0);
  const float4 b = *(const float4*)(conv_b + c0);
  ushort4 pk;
  pk.x = f2b(v.x + b.x); pk.y = f2b(v.y + b.y);
  pk.z = f2b(v.z + b.z); pk.w = f2b(v.w + b.w);
  *(ushort4*)(qeb + row * KQ + c0) = pk;
}

// ---------- generic GEMM skeleton: C[28672, 256] = A[28672,KP]bf16 * Bt[256,KP]^T ----------
// Double-buffered counted-vmcnt pipeline; 4 global_load_lds per wave per K-step.
// A staging padded to 128 rows (row group 7 garbage, never read by MFMA).
// MODE 0: bias is PER-N (biasHP[n*256+col], includes hp_b0 + code-part). MODE 1: per-n bias2.
template <int MODE, int KP, int KC>
__global__ __launch_bounds__(256) void gemm_kernel(
    const u16* __restrict__ A, const u16* __restrict__ Bt,
    const float* __restrict__ bias, const float* __restrict__ vec,
    float* __restrict__ outF, u16* __restrict__ outB) {
  __shared__ __align__(16) u16 lA[2][128 * 32];
  __shared__ __align__(16) u16 lB[2][128 * 32];
  int tid = threadIdx.x, lane = tid & 63, w = tid >> 6;
  int bx = blockIdx.x, by = blockIdx.y;
  int r0 = bx * 112;
  int cBase = by * 128;
  int kb = (((lane & 3) ^ ((lane >> 3) & 3)) << 3);   // XOR-swizzled source chunk
  int rA0 = r0 + w * 16 + (lane >> 2);
  int rA1 = r0 + (w + 4) * 16 + (lane >> 2);          // group 7 (rows 112..127) = pad
  const u16* gA0 = A + (size_t)rA0 * KP + kb;
  const u16* gA1 = A + (size_t)rA1 * KP + kb;
  int cB0 = cBase + w * 16 + (lane >> 2);
  int cB1 = cBase + (w + 4) * 16 + (lane >> 2);
  const u16* gB0 = Bt + (size_t)cB0 * KP + kb;
  const u16* gB1 = Bt + (size_t)cB1 * KP + kb;

  f32x4 acc[7][2];
#pragma unroll
  for (int mt = 0; mt < 7; ++mt)
#pragma unroll
    for (int j = 0; j < 2; ++j) acc[mt][j] = (f32x4){0.f, 0.f, 0.f, 0.f};
  int colW = w * 32;
  int l = lane & 15, q = lane >> 4;
  int co = ((q ^ ((l >> 1) & 3)) << 3);

  auto STAGE = [&](int buf, int cb) {
    g2l16(gA0 + cb * 32, &lA[buf][w * 512]);
    g2l16(gA1 + cb * 32, &lA[buf][(w + 4) * 512]);
    g2l16(gB0 + cb * 32, &lB[buf][w * 512]);
    g2l16(gB1 + cb * 32, &lB[buf][(w + 4) * 512]);
  };

  auto COMPUTE = [&](int cur) {
    bf16x8 af[7];
#pragma unroll
    for (int mt = 0; mt < 7; ++mt)
      af[mt] = *(const bf16x8*)&lA[cur][(mt * 16 + l) * 32 + co];
#pragma unroll
    for (int j = 0; j < 2; ++j) {
      bf16x8 bfr = *(const bf16x8*)&lB[cur][(colW + j * 16 + l) * 32 + co];
#pragma unroll
      for (int mt = 0; mt < 7; ++mt)
        acc[mt][j] = __builtin_amdgcn_mfma_f32_16x16x32_bf16(af[mt], bfr, acc[mt][j], 0, 0, 0);
    }
  };

  STAGE(0, 0);
#pragma unroll
  for (int it = 0; it < KC - 1; ++it) {
    STAGE((it & 1) ^ 1, it + 1);
    asm volatile("s_waitcnt vmcnt(4)" ::: "memory");   // prev step's 4 loads done; 4 in flight
    __builtin_amdgcn_s_barrier();
    __builtin_amdgcn_sched_barrier(0);
    COMPUTE(it & 1);
    __builtin_amdgcn_s_barrier();                      // all reads done before next STAGE overwrites
    __builtin_amdgcn_sched_barrier(0);
  }
  asm volatile("s_waitcnt vmcnt(0)" ::: "memory");
  __builtin_amdgcn_s_barrier();
  __builtin_amdgcn_sched_barrier(0);
  COMPUTE((KC - 1) & 1);

  int q4 = lane >> 4, c = lane & 15;
  if (MODE == 0) {
    int n = bx >> 1;
    float attp[7][4];
#pragma unroll
    for (int mt = 0; mt < 7; ++mt)
#pragma unroll
      for (int r = 0; r < 4; ++r) attp[mt][r] = 0.f;
#pragma unroll
    for (int j = 0; j < 2; ++j) {
      int col = cBase + colW + j * 16 + c;
      float b0 = bias[n * 256 + col], w1 = vec[col];
#pragma unroll
      for (int mt = 0; mt < 7; ++mt)
#pragma unroll
        for (int r = 0; r < 4; ++r) {
          float v = fmaxf(acc[mt][j][r] + b0, 0.f);
          attp[mt][r] += v * w1;
        }
    }
#pragma unroll
    for (int mt = 0; mt < 7; ++mt)
#pragma unroll
      for (int r = 0; r < 4; ++r) {
        float p = attp[mt][r];
        p += __shfl_xor(p, 1, 64);
        p += __shfl_xor(p, 2, 64);
        p += __shfl_xor(p, 4, 64);
        p += __shfl_xor(p, 8, 64);
        if (c == 0) atomicAdd(&outF[r0 + mt * 16 + q4 * 4 + r], p);
      }
  } else if (MODE == 1) {
    int n = bx >> 1;
#pragma unroll
    for (int mt = 0; mt < 7; ++mt)
#pragma unroll
      for (int j = 0; j < 2; ++j) {
        int col = cBase + colW + j * 16 + c;
        float b = bias[n * 256 + col];
#pragma unroll
        for (int r = 0; r < 4; ++r) {
          int row = r0 + mt * 16 + q4 * 4 + r;
          outB[(size_t)row * 256 + col] = f2b(fmaxf(acc[mt][j][r] + b, 0.f));
        }
      }
  } else {
    int n = bx >> 1;
    int ob = (bx & 1) * 112;
#pragma unroll
    for (int j = 0; j < 2; ++j) {
      int col = cBase + colW + j * 16 + c;
      float b = bias[col];
      float sum = 0.f;
#pragma unroll
      for (int mt = 0; mt < 7; ++mt)
#pragma unroll
        for (int r = 0; r < 4; ++r) {
          int o = ob + mt * 16 + q4 * 4 + r;
          if (o < 196) sum += fmaxf(acc[mt][j][r] + b, 0.f);
        }
      sum += __shfl_xor(sum, 16, 64);
      sum += __shfl_xor(sum, 32, 64);
      if (q4 == 0) atomicAdd(&outF[n * 256 + col], sum);
    }
  }
}

// ---------- K5: softmax over objects, soft-select, per-n bias2 (incl. code part) ----------
__global__ __launch_bounds__(256) void sel_kernel(
    const float* __restrict__ att, const u16* __restrict__ qeb,
    const float* __restrict__ gt_w0, const float* __restrict__ gt_b0,
    const float* __restrict__ code, float* __restrict__ bias2) {
  int n = blockIdx.x, t = threadIdx.x;
  int w = t >> 6, lane = t & 63;
  __shared__ u16 sq[196][130];
  __shared__ float sm[196];
  __shared__ float sel[130];
  __shared__ float red[8];
  // cooperative stage of qeb[n, 0:196, 0:130]
  const u16* base = qeb + (size_t)n * 224 * KQ;
  for (int o = w; o < 196; o += 4) {
    const u16* rowp = base + (size_t)o * KQ;
    for (int c = lane; c < 130; c += 64) sq[o][c] = rowp[c];
  }
  float a = (t < 196) ? att[n * 224 + t] : -1e30f;
  float m = a;
  for (int mask = 1; mask < 64; mask <<= 1) m = fmaxf(m, __shfl_xor(m, mask, 64));
  if (lane == 0) red[w] = m;
  __syncthreads();
  float M = fmaxf(fmaxf(red[0], red[1]), fmaxf(red[2], red[3]));
  float e = (t < 196) ? expf(a - M) : 0.f;
  float sAcc = e;
  for (int mask = 1; mask < 64; mask <<= 1) sAcc += __shfl_xor(sAcc, mask, 64);
  if (lane == 0) red[4 + w] = sAcc;
  __syncthreads();
  float S = red[4] + red[5] + red[6] + red[7];
  if (t < 196) sm[t] = e / S;
  __syncthreads();
  if (t < 130) {
    float acc = 0.f;
    for (int o = 0; o < 196; ++o) acc += sm[o] * b2f(sq[o][t]);
    sel[t] = acc;
  }
  __syncthreads();
  float acc2 = gt_b0[t];
  for (int d = 0; d < 130; ++d) acc2 += sel[d] * gt_w0[(258 + d) * 256 + t];
  for (int d = 0; d < 128; ++d) acc2 += code[n * 128 + d] * gt_w0[(130 + d) * 256 + t];
  bias2[n * 256 + t] = acc2;
}

// ---------- K8: f_phi ----------
__global__ __launch_bounds__(256) void fphi(
    const float* __restrict__ relations, const float* __restrict__ fp_w0,
    const float* __restrict__ fp_b0, const float* __restrict__ fp_w1,
    const float* __restrict__ fp_b1, float* __restrict__ out) {
  int n = blockIdx.x, t = threadIdx.x;
  __shared__ float rel[256];
  __shared__ float f[256];
  rel[t] = relations[n * 256 + t];
  __syncthreads();
  float acc = fp_b0[t];
  for (int k = 0; k < 256; ++k) acc += rel[k] * fp_w0[k * 256 + t];
  f[t] = fmaxf(acc, 0.f);
  __syncthreads();
  if (t < 32) {
    float o = fp_b1[0];
    for (int k = 0; k < 256; ++k) o += f[k] * fp_w1[k * 32 + t];
    out[n * 32 + t] = o;
  }
}

extern "C" void kernel_launch(void* const* d_in, const int* in_sizes, int n_in,
                              void* d_out, int out_size, void* d_ws, size_t ws_size,
                              hipStream_t stream) {
  const float* image = (const float*)d_in[0];
  const float* code = (const float*)d_in[1];
  const float* conv_w = (const float*)d_in[2];
  const float* conv_b = (const float*)d_in[3];
  const float* hp_w0 = (const float*)d_in[4];
  const float* hp_b0 = (const float*)d_in[5];
  const float* hp_w1 = (const float*)d_in[6];
  /* hp_b1: softmax shift-invariant, dropped */
  const float* gt_w0 = (const float*)d_in[8];
  const float* gt_b0 = (const float*)d_in[9];
  const float* gt_w1 = (const float*)d_in[10];
  const float* gt_b1 = (const float*)d_in[11];
  const float* fp_w0 = (const float*)d_in[12];
  const float* fp_b0 = (const float*)d_in[13];
  const float* fp_w1 = (const float*)d_in[14];
  const float* fp_b1 = (const float*)d_in[15];
  float* out = (float*)d_out;

  char* p = (char*)d_ws;
  u16* imgT = (u16*)p;   p += (size_t)128 * 256 * 1024 * 2;   // 67.1 MB
  u16* W2 = (u16*)p;     p += (size_t)9 * 128 * 1024 * 2;     // 2.36 MB
  u16* qeb = (u16*)p;    p += (size_t)ROWS * KQ * 2;          // 9.2 MB
  u16* hp_w0t = (u16*)p; p += (size_t)256 * KQ * 2;
  u16* gt_w0t = (u16*)p; p += (size_t)256 * KQ * 2;
  u16* gt_w1t = (u16*)p; p += (size_t)256 * 256 * 2;
  float* att = (float*)p;    p += (size_t)ROWS * 4;
  float* bias2 = (float*)p;  p += (size_t)128 * 256 * 4;
  float* biasHP = (float*)p; p += (size_t)128 * 256 * 4;
  float* convAcc = (float*)p; p += (size_t)ROWS * 128 * 4;    // 14.7 MB; reused as g1
  float* relations = (float*)p; p += (size_t)128 * 256 * 4;
  u16* g1 = (u16*)convAcc;   // alias: convAcc dead after conv_fix, g1 born at MODE1

  hipMemsetAsync(att, 0, (size_t)ROWS * 4, stream);
  hipMemsetAsync(relations, 0, (size_t)128 * 256 * 4, stream);
  hipMemsetAsync(convAcc, 0, (size_t)ROWS * 128 * 4, stream);

  // 9*128*1024 + 256*160 + 256*160 + 256*256 + 128*256 = 1,359,872 = 5312 * 256
  prep_weights<<<5312, 256, 0, stream>>>(conv_w, hp_w0, gt_w0, gt_w1, hp_b0, code,
                                         W2, hp_w0t, gt_w0t, gt_w1t, biasHP);
  prep_img<<<2048, 256, 0, stream>>>(image, imgT);
  fill_qe<<<1344, 256, 0, stream>>>(qeb);   // ROWS*8 + 3584*32 = 344,064 = 1344*256
  conv_gemm<<<768, 256, 0, stream>>>(imgT, W2, convAcc);
  conv_fix<<<3136, 256, 0, stream>>>(convAcc, conv_b, qeb);
  gemm_kernel<0, KQ, 5><<<dim3(256, 2), 256, 0, stream>>>(qeb, hp_w0t, biasHP, hp_w1, att, nullptr);
  sel_kernel<<<128, 256, 0, stream>>>(att, qeb, gt_w0, gt_b0, code, bias2);
  gemm_kernel<1, KQ, 5><<<dim3(256, 2), 256, 0, stream>>>(qeb, gt_w0t, bias2, nullptr, nullptr, g1);
  gemm_kernel<2, 256, 8><<<dim3(256, 2), 256, 0, stream>>>(g1, gt_w1t, gt_b1, nullptr, relations, nullptr);
  fphi<<<128, 256, 0, stream>>>(relations, fp_w0, fp_b0, fp_w1, fp_b1, out);
}

// Round 6
// 381.819 us; speedup vs baseline: 1.1363x; 1.0399x over previous
//
#include <hip/hip_runtime.h>
#include <stdint.h>

typedef unsigned short u16;
typedef __bf16 bf16x8 __attribute__((ext_vector_type(8)));
typedef float f32x4 __attribute__((ext_vector_type(4)));

// ---------- helpers ----------
__device__ __forceinline__ u16 f2b(float f) {
  union { float f; uint32_t u; } v; v.f = f;
  uint32_t r = v.u + 0x7fffu + ((v.u >> 16) & 1u);
  return (u16)(r >> 16);
}
__device__ __forceinline__ float b2f(u16 b) {
  union { float f; uint32_t u; } v; v.u = ((uint32_t)b) << 16;
  return v.f;
}
// async 16B/lane global->LDS (dest = uniform base + lane*16)
__device__ __forceinline__ void g2l16(const void* g, void* l) {
  __builtin_amdgcn_global_load_lds(
      (const __attribute__((address_space(1))) void*)g,
      (__attribute__((address_space(3))) void*)l, 16, 0, 0);
}

#define N_SAMP 128
#define OPAD   224
#define ROWS   (N_SAMP * OPAD)   // 28672
#define KQ     160               // qeb K: 128 conv + 2 coords + 30 zero pad

// ---------- K0a: W2 repack via LDS transpose (coalesced conv_w read) ----------
// 512 blocks x 256 pairs; block reads 2304 contiguous f32, writes 9 tap-planes coalesced.
__global__ __launch_bounds__(256) void prep_w2(const float* __restrict__ conv_w,
                                               u16* __restrict__ W2) {
  __shared__ float ls[2304];
  int p0 = blockIdx.x << 8;
  int t = threadIdx.x;
  const float* src = conv_w + (size_t)p0 * 9;
#pragma unroll
  for (int i = 0; i < 9; ++i) ls[t + i * 256] = src[t + i * 256];
  __syncthreads();
#pragma unroll
  for (int s = 0; s < 9; ++s)
    W2[s * 131072 + p0 + t] = f2b(ls[t * 9 + s]);   // ls[t*9+s]: 9 coprime 32 -> conflict-free
}

// ---------- K0c: range-dispatched init (small repacks + biases + qeb + zero fills) ----------
#define R_HP   40960      // hp_w0t 256*160
#define R_GT0  40960      // gt_w0t 256*160
#define R_GT1  65536      // gt_w1t 256*256
#define R_BHP  32768      // biasHP 128*256 (128-iter loop)
#define R_BGT  32768      // biasGT 128*256 (128-iter loop)
#define R_QC   (ROWS * 8) // qeb coord quads (cols 128..159)
#define R_QP   114688     // qeb pad rows: 3584 rows x 32 quads (cols 0..127)
#define R_ATT  7168       // att zero, float4
#define R_REL  8192       // relations zero, float4
#define R_CVA  917504     // convAcc zero, float4
// total 1,489,920 = 5820 * 256
__global__ __launch_bounds__(256) void init_misc(
    const float* __restrict__ hp_w0, const float* __restrict__ gt_w0,
    const float* __restrict__ gt_w1, const float* __restrict__ hp_b0,
    const float* __restrict__ gt_b0, const float* __restrict__ code,
    u16* __restrict__ hp_w0t, u16* __restrict__ gt_w0t, u16* __restrict__ gt_w1t,
    float* __restrict__ biasHP, float* __restrict__ biasGT, u16* __restrict__ qeb,
    float* __restrict__ att, float* __restrict__ relations,
    float* __restrict__ convAcc) {
  int idx = blockIdx.x * 256 + threadIdx.x;
  if (idx < R_HP) {
    int nn = idx / KQ, kk = idx % KQ;
    hp_w0t[idx] = (kk < 130) ? f2b(hp_w0[kk * 256 + nn]) : (u16)0;
    return;
  }
  idx -= R_HP;
  if (idx < R_GT0) {
    int nn = idx / KQ, kk = idx % KQ;
    gt_w0t[idx] = (kk < 130) ? f2b(gt_w0[kk * 256 + nn]) : (u16)0;
    return;
  }
  idx -= R_GT0;
  if (idx < R_GT1) {
    int nn = idx >> 8, kk = idx & 255;
    gt_w1t[idx] = f2b(gt_w1[kk * 256 + nn]);
    return;
  }
  idx -= R_GT1;
  if (idx < R_BHP) {
    int n = idx >> 8, t = idx & 255;
    float acc = hp_b0[t];
    for (int d = 0; d < 128; ++d) acc += code[n * 128 + d] * hp_w0[(130 + d) * 256 + t];
    biasHP[idx] = acc;
    return;
  }
  idx -= R_BHP;
  if (idx < R_BGT) {
    int n = idx >> 8, t = idx & 255;
    float acc = gt_b0[t];
    for (int d = 0; d < 128; ++d) acc += code[n * 128 + d] * gt_w0[(130 + d) * 256 + t];
    biasGT[idx] = acc;
    return;
  }
  idx -= R_BGT;
  if (idx < R_QC) {
    int row = idx >> 3, qd = idx & 7;
    int o = row % 224;
    ushort4 v = {0, 0, 0, 0};
    if (o < 196 && qd == 0) {
      int y = o / 14, x = o % 14;
      v.x = f2b(-1.f + 2.f * y / 13.f);
      v.y = f2b(-1.f + 2.f * x / 13.f);
    }
    *(ushort4*)(qeb + (size_t)row * KQ + 128 + qd * 4) = v;
    return;
  }
  idx -= R_QC;
  if (idx < R_QP) {
    int pr = idx >> 5, qd = idx & 31;
    int row = (pr / 28) * 224 + 196 + (pr % 28);
    *(ushort4*)(qeb + (size_t)row * KQ + qd * 4) = (ushort4){0, 0, 0, 0};
    return;
  }
  idx -= R_QP;
  if (idx < R_ATT) { *((float4*)att + idx) = (float4){0.f, 0.f, 0.f, 0.f}; return; }
  idx -= R_ATT;
  if (idx < R_REL) { *((float4*)relations + idx) = (float4){0.f, 0.f, 0.f, 0.f}; return; }
  idx -= R_REL;
  *((float4*)convAcc + idx) = (float4){0.f, 0.f, 0.f, 0.f};
}

// ---------- K0b: image -> imgT[n][256 sp (16x16 zero-bordered)][1024 cin] bf16 ----------
// Writes vectorized: uint4 = 8 bf16 = 16 B/lane (was 2 B/lane scalar u16).
__global__ __launch_bounds__(256) void prep_img(const float* __restrict__ image,
                                                u16* __restrict__ imgT) {
  __shared__ float t[64][197];
  int n = blockIdx.x >> 4;
  int cin0 = (blockIdx.x & 15) * 64;
  const float* src = image + ((size_t)n * 1024 + cin0) * 196;
  for (int e = threadIdx.x; e < 64 * 196; e += 256) {
    int c = e / 196, sp = e % 196;
    t[c][sp] = src[c * 196 + sp];
  }
  __syncthreads();
#pragma unroll
  for (int i = 0; i < 8; ++i) {
    int qid = threadIdx.x + i * 256;     // 2048 chunks of 8 bf16
    int spg = qid >> 3, qd = qid & 7;
    int gy = spg >> 4, gx = spg & 15;
    uint4 pk = {0u, 0u, 0u, 0u};
    if (gy >= 1 && gy <= 14 && gx >= 1 && gx <= 14) {
      int sp = (gy - 1) * 14 + (gx - 1);
      uint32_t vv[8];
#pragma unroll
      for (int j = 0; j < 8; ++j) vv[j] = f2b(t[qd * 8 + j][sp]);
      pk.x = vv[0] | (vv[1] << 16);
      pk.y = vv[2] | (vv[3] << 16);
      pk.z = vv[4] | (vv[5] << 16);
      pk.w = vv[6] | (vv[7] << 16);
    }
    *(uint4*)(imgT + (((size_t)(n * 256 + spg)) << 10) + cin0 + qd * 8) = pk;
  }
}

// ---------- K1: conv as implicit GEMM, split-K x3 (round-0 proven structure) ----------
// grid 768 = 8 xcd * (16 ngrp * 2 ohalf * 3 kslice); BK=64; swizzled LDS.
__global__ __launch_bounds__(256) void conv_gemm(
    const u16* __restrict__ imgT, const u16* __restrict__ W2,
    float* __restrict__ convAcc) {
  __shared__ __align__(16) u16 lA[112 * 64];
  __shared__ __align__(16) u16 lB[128 * 64];
  int tid = threadIdx.x, lane = tid & 63, w = tid >> 6;
  int wg = blockIdx.x;
  int xcd = wg & 7, grp = wg >> 3;          // same-n blocks land on same XCD
  int n = ((grp / 6) << 3) | xcd;
  int r6 = grp % 6;
  int oh = r6 / 3, ks = r6 % 3;
  int oBase = oh * 112;
  size_t nBase = (size_t)n << 8;
  int rowIn = lane >> 3;                    // row within 8-row staging instr
  int cA = ((lane & 7) ^ rowIn) << 3;       // XOR-swizzled chunk offset (elems)

  // A-row spatial precompute for staging instrs t = w + 4*ii
  int yxA[4];
  for (int ii = 0; ii < 4; ++ii) {
    int t = w + ii * 4;
    int o = oBase + t * 8 + rowIn;
    bool valid = o < 196;
    int y = o / 14, x = o - y * 14;
    yxA[ii] = valid ? (y * 16 + x) : 0;    // invalid rows read border zeros / garbage; outputs discarded
  }

  f32x4 acc[7][2];
#pragma unroll
  for (int mt = 0; mt < 7; ++mt)
#pragma unroll
    for (int j = 0; j < 2; ++j) acc[mt][j] = (f32x4){0.f, 0.f, 0.f, 0.f};

  int l = lane & 15, q = lane >> 4;
  for (int si = 0; si < 3; ++si) {
    int s = ks * 3 + si;
    int off = (s / 3) * 16 + (s % 3);
    const u16* Ws = W2 + ((size_t)(s * 128) << 10);
    for (int cb = 0; cb < 16; ++cb) {
      int k0 = cb << 6;
      __syncthreads();
      // stage A: 14 instrs (waves 0,1: 4 each; waves 2,3: 3 each)
      g2l16(imgT + ((nBase + (size_t)(yxA[0] + off)) << 10) + k0 + cA, &lA[(w) * 512]);
      g2l16(imgT + ((nBase + (size_t)(yxA[1] + off)) << 10) + k0 + cA, &lA[(w + 4) * 512]);
      g2l16(imgT + ((nBase + (size_t)(yxA[2] + off)) << 10) + k0 + cA, &lA[(w + 8) * 512]);
      if (w < 2)
        g2l16(imgT + ((nBase + (size_t)(yxA[3] + off)) << 10) + k0 + cA, &lA[(w + 12) * 512]);
      // stage B: 16 instrs (4 per wave)
#pragma unroll
      for (int ii = 0; ii < 4; ++ii) {
        int t = w + ii * 4;
        g2l16(Ws + ((size_t)(t * 8 + rowIn) << 10) + k0 + cA, &lB[t * 512]);
      }
      __syncthreads();
#pragma unroll
      for (int kk = 0; kk < 2; ++kk) {
        int co = ((((kk << 2) | q) ^ (l & 7)) << 3);
        bf16x8 af[7];
#pragma unroll
        for (int mt = 0; mt < 7; ++mt)
          af[mt] = *(const bf16x8*)&lA[(mt * 16 + l) * 64 + co];
#pragma unroll
        for (int jj = 0; jj < 2; ++jj) {
          bf16x8 bb = *(const bf16x8*)&lB[(w * 32 + jj * 16 + l) * 64 + co];
#pragma unroll
          for (int mt = 0; mt < 7; ++mt)
            acc[mt][jj] = __builtin_amdgcn_mfma_f32_16x16x32_bf16(af[mt], bb, acc[mt][jj], 0, 0, 0);
        }
      }
    }
  }
  // epilogue: atomic fp32 accumulate of the K-slice partial
#pragma unroll
  for (int mt = 0; mt < 7; ++mt) {
    int o = oBase + mt * 16 + q * 4;
#pragma unroll
    for (int r4 = 0; r4 < 4; ++r4) {
      if (o + r4 < 196) {
        float* dst = convAcc + (size_t)(n * 224 + o + r4) * 128 + w * 32 + l;
        atomicAdd(dst, acc[mt][0][r4]);
        atomicAdd(dst + 16, acc[mt][1][r4]);
      }
    }
  }
}

// ---------- K1b: convAcc + bias -> qeb bf16 cols 0..127 ----------
__global__ __launch_bounds__(256) void conv_fix(
    const float* __restrict__ convAcc, const float* __restrict__ conv_b,
    u16* __restrict__ qeb) {
  int idx = blockIdx.x * 256 + threadIdx.x;   // 128*196*32
  int row196 = idx >> 5;
  int c0 = (idx & 31) << 2;
  int n = row196 / 196, o = row196 - n * 196;
  size_t row = (size_t)(n * 224 + o);
  const float4 v = *(const float4*)(convAcc + (row << 7) + c0);
  const float4 b = *(const float4*)(conv_b + c0);
  ushort4 pk;
  pk.x = f2b(v.x + b.x); pk.y = f2b(v.y + b.y);
  pk.z = f2b(v.z + b.z); pk.w = f2b(v.w + b.w);
  *(ushort4*)(qeb + row * KQ + c0) = pk;
}

// ---------- generic GEMM skeleton: C[28672, 256] = A[28672,KP]bf16 * Bt[256,KP]^T ----------
// Double-buffered counted-vmcnt pipeline; 4 global_load_lds per wave per K-step.
// A staging padded to 128 rows (row group 7 garbage, never read by MFMA).
// MODE 0: bias per-n (biasHP incl. code part). MODE 1: per-n bias2.
template <int MODE, int KP, int KC>
__global__ __launch_bounds__(256) void gemm_kernel(
    const u16* __restrict__ A, const u16* __restrict__ Bt,
    const float* __restrict__ bias, const float* __restrict__ vec,
    float* __restrict__ outF, u16* __restrict__ outB) {
  __shared__ __align__(16) u16 lA[2][128 * 32];
  __shared__ __align__(16) u16 lB[2][128 * 32];
  int tid = threadIdx.x, lane = tid & 63, w = tid >> 6;
  int bx = blockIdx.x, by = blockIdx.y;
  int r0 = bx * 112;
  int cBase = by * 128;
  int kb = (((lane & 3) ^ ((lane >> 3) & 3)) << 3);   // XOR-swizzled source chunk
  int rA0 = r0 + w * 16 + (lane >> 2);
  int rA1 = r0 + (w + 4) * 16 + (lane >> 2);          // group 7 (rows 112..127) = pad
  const u16* gA0 = A + (size_t)rA0 * KP + kb;
  const u16* gA1 = A + (size_t)rA1 * KP + kb;
  int cB0 = cBase + w * 16 + (lane >> 2);
  int cB1 = cBase + (w + 4) * 16 + (lane >> 2);
  const u16* gB0 = Bt + (size_t)cB0 * KP + kb;
  const u16* gB1 = Bt + (size_t)cB1 * KP + kb;

  f32x4 acc[7][2];
#pragma unroll
  for (int mt = 0; mt < 7; ++mt)
#pragma unroll
    for (int j = 0; j < 2; ++j) acc[mt][j] = (f32x4){0.f, 0.f, 0.f, 0.f};
  int colW = w * 32;
  int l = lane & 15, q = lane >> 4;
  int co = ((q ^ ((l >> 1) & 3)) << 3);

  auto STAGE = [&](int buf, int cb) {
    g2l16(gA0 + cb * 32, &lA[buf][w * 512]);
    g2l16(gA1 + cb * 32, &lA[buf][(w + 4) * 512]);
    g2l16(gB0 + cb * 32, &lB[buf][w * 512]);
    g2l16(gB1 + cb * 32, &lB[buf][(w + 4) * 512]);
  };

  auto COMPUTE = [&](int cur) {
    bf16x8 af[7];
#pragma unroll
    for (int mt = 0; mt < 7; ++mt)
      af[mt] = *(const bf16x8*)&lA[cur][(mt * 16 + l) * 32 + co];
#pragma unroll
    for (int j = 0; j < 2; ++j) {
      bf16x8 bfr = *(const bf16x8*)&lB[cur][(colW + j * 16 + l) * 32 + co];
#pragma unroll
      for (int mt = 0; mt < 7; ++mt)
        acc[mt][j] = __builtin_amdgcn_mfma_f32_16x16x32_bf16(af[mt], bfr, acc[mt][j], 0, 0, 0);
    }
  };

  STAGE(0, 0);
#pragma unroll
  for (int it = 0; it < KC - 1; ++it) {
    STAGE((it & 1) ^ 1, it + 1);
    asm volatile("s_waitcnt vmcnt(4)" ::: "memory");   // prev step's 4 loads done; 4 in flight
    __builtin_amdgcn_s_barrier();
    __builtin_amdgcn_sched_barrier(0);
    COMPUTE(it & 1);
    __builtin_amdgcn_s_barrier();                      // all reads done before next STAGE overwrites
    __builtin_amdgcn_sched_barrier(0);
  }
  asm volatile("s_waitcnt vmcnt(0)" ::: "memory");
  __builtin_amdgcn_s_barrier();
  __builtin_amdgcn_sched_barrier(0);
  COMPUTE((KC - 1) & 1);

  int q4 = lane >> 4, c = lane & 15;
  if (MODE == 0) {
    int n = bx >> 1;
    float attp[7][4];
#pragma unroll
    for (int mt = 0; mt < 7; ++mt)
#pragma unroll
      for (int r = 0; r < 4; ++r) attp[mt][r] = 0.f;
#pragma unroll
    for (int j = 0; j < 2; ++j) {
      int col = cBase + colW + j * 16 + c;
      float b0 = bias[n * 256 + col], w1 = vec[col];
#pragma unroll
      for (int mt = 0; mt < 7; ++mt)
#pragma unroll
        for (int r = 0; r < 4; ++r) {
          float v = fmaxf(acc[mt][j][r] + b0, 0.f);
          attp[mt][r] += v * w1;
        }
    }
#pragma unroll
    for (int mt = 0; mt < 7; ++mt)
#pragma unroll
      for (int r = 0; r < 4; ++r) {
        float p = attp[mt][r];
        p += __shfl_xor(p, 1, 64);
        p += __shfl_xor(p, 2, 64);
        p += __shfl_xor(p, 4, 64);
        p += __shfl_xor(p, 8, 64);
        if (c == 0) atomicAdd(&outF[r0 + mt * 16 + q4 * 4 + r], p);
      }
  } else if (MODE == 1) {
    int n = bx >> 1;
#pragma unroll
    for (int mt = 0; mt < 7; ++mt)
#pragma unroll
      for (int j = 0; j < 2; ++j) {
        int col = cBase + colW + j * 16 + c;
        float b = bias[n * 256 + col];
#pragma unroll
        for (int r = 0; r < 4; ++r) {
          int row = r0 + mt * 16 + q4 * 4 + r;
          outB[(size_t)row * 256 + col] = f2b(fmaxf(acc[mt][j][r] + b, 0.f));
        }
      }
  } else {
    int n = bx >> 1;
    int ob = (bx & 1) * 112;
#pragma unroll
    for (int j = 0; j < 2; ++j) {
      int col = cBase + colW + j * 16 + c;
      float b = bias[col];
      float sum = 0.f;
#pragma unroll
      for (int mt = 0; mt < 7; ++mt)
#pragma unroll
        for (int r = 0; r < 4; ++r) {
          int o = ob + mt * 16 + q4 * 4 + r;
          if (o < 196) sum += fmaxf(acc[mt][j][r] + b, 0.f);
        }
      sum += __shfl_xor(sum, 16, 64);
      sum += __shfl_xor(sum, 32, 64);
      if (q4 == 0) atomicAdd(&outF[n * 256 + col], sum);
    }
  }
}

// ---------- K5: softmax over objects, soft-select, per-n bias2 (code part precomputed) ----------
__global__ __launch_bounds__(256) void sel_kernel(
    const float* __restrict__ att, const u16* __restrict__ qeb,
    const float* __restrict__ gt_w0, const float* __restrict__ biasGT,
    float* __restrict__ bias2) {
  int n = blockIdx.x, t = threadIdx.x;
  int w = t >> 6, lane = t & 63;
  __shared__ u16 sq[196][130];
  __shared__ float sm[196];
  __shared__ float sel[130];
  __shared__ float red[8];
  // cooperative stage of qeb[n, 0:196, 0:130]
  const u16* base = qeb + (size_t)n * 224 * KQ;
  for (int o = w; o < 196; o += 4) {
    const u16* rowp = base + (size_t)o * KQ;
    for (int c = lane; c < 130; c += 64) sq[o][c] = rowp[c];
  }
  float a = (t < 196) ? att[n * 224 + t] : -1e30f;
  float m = a;
  for (int mask = 1; mask < 64; mask <<= 1) m = fmaxf(m, __shfl_xor(m, mask, 64));
  if (lane == 0) red[w] = m;
  __syncthreads();
  float M = fmaxf(fmaxf(red[0], red[1]), fmaxf(red[2], red[3]));
  float e = (t < 196) ? expf(a - M) : 0.f;
  float sAcc = e;
  for (int mask = 1; mask < 64; mask <<= 1) sAcc += __shfl_xor(sAcc, mask, 64);
  if (lane == 0) red[4 + w] = sAcc;
  __syncthreads();
  float S = red[4] + red[5] + red[6] + red[7];
  if (t < 196) sm[t] = e / S;
  __syncthreads();
  if (t < 130) {
    float acc = 0.f;
    for (int o = 0; o < 196; ++o) acc += sm[o] * b2f(sq[o][t]);
    sel[t] = acc;
  }
  __syncthreads();
  float acc2 = biasGT[n * 256 + t];
  for (int d = 0; d < 130; ++d) acc2 += sel[d] * gt_w0[(258 + d) * 256 + t];
  bias2[n * 256 + t] = acc2;
}

// ---------- K8: f_phi ----------
__global__ __launch_bounds__(256) void fphi(
    const float* __restrict__ relations, const float* __restrict__ fp_w0,
    const float* __restrict__ fp_b0, const float* __restrict__ fp_w1,
    const float* __restrict__ fp_b1, float* __restrict__ out) {
  int n = blockIdx.x, t = threadIdx.x;
  __shared__ float rel[256];
  __shared__ float f[256];
  rel[t] = relations[n * 256 + t];
  __syncthreads();
  float acc = fp_b0[t];
  for (int k = 0; k < 256; ++k) acc += rel[k] * fp_w0[k * 256 + t];
  f[t] = fmaxf(acc, 0.f);
  __syncthreads();
  if (t < 32) {
    float o = fp_b1[0];
    for (int k = 0; k < 256; ++k) o += f[k] * fp_w1[k * 32 + t];
    out[n * 32 + t] = o;
  }
}

extern "C" void kernel_launch(void* const* d_in, const int* in_sizes, int n_in,
                              void* d_out, int out_size, void* d_ws, size_t ws_size,
                              hipStream_t stream) {
  const float* image = (const float*)d_in[0];
  const float* code = (const float*)d_in[1];
  const float* conv_w = (const float*)d_in[2];
  const float* conv_b = (const float*)d_in[3];
  const float* hp_w0 = (const float*)d_in[4];
  const float* hp_b0 = (const float*)d_in[5];
  const float* hp_w1 = (const float*)d_in[6];
  /* hp_b1: softmax shift-invariant, dropped */
  const float* gt_w0 = (const float*)d_in[8];
  const float* gt_b0 = (const float*)d_in[9];
  const float* gt_w1 = (const float*)d_in[10];
  const float* gt_b1 = (const float*)d_in[11];
  const float* fp_w0 = (const float*)d_in[12];
  const float* fp_b0 = (const float*)d_in[13];
  const float* fp_w1 = (const float*)d_in[14];
  const float* fp_b1 = (const float*)d_in[15];
  float* out = (float*)d_out;

  char* p = (char*)d_ws;
  u16* imgT = (u16*)p;   p += (size_t)128 * 256 * 1024 * 2;   // 67.1 MB
  u16* W2 = (u16*)p;     p += (size_t)9 * 128 * 1024 * 2;     // 2.36 MB
  u16* qeb = (u16*)p;    p += (size_t)ROWS * KQ * 2;          // 9.2 MB
  u16* hp_w0t = (u16*)p; p += (size_t)256 * KQ * 2;
  u16* gt_w0t = (u16*)p; p += (size_t)256 * KQ * 2;
  u16* gt_w1t = (u16*)p; p += (size_t)256 * 256 * 2;
  float* att = (float*)p;    p += (size_t)ROWS * 4;
  float* bias2 = (float*)p;  p += (size_t)128 * 256 * 4;
  float* biasHP = (float*)p; p += (size_t)128 * 256 * 4;
  float* biasGT = (float*)p; p += (size_t)128 * 256 * 4;
  float* convAcc = (float*)p; p += (size_t)ROWS * 128 * 4;    // 14.7 MB; reused as g1
  float* relations = (float*)p; p += (size_t)128 * 256 * 4;
  u16* g1 = (u16*)convAcc;   // alias: convAcc dead after conv_fix, g1 born at MODE1

  init_misc<<<5820, 256, 0, stream>>>(hp_w0, gt_w0, gt_w1, hp_b0, gt_b0, code,
                                      hp_w0t, gt_w0t, gt_w1t, biasHP, biasGT, qeb,
                                      att, relations, convAcc);
  prep_w2<<<512, 256, 0, stream>>>(conv_w, W2);
  prep_img<<<2048, 256, 0, stream>>>(image, imgT);
  conv_gemm<<<768, 256, 0, stream>>>(imgT, W2, convAcc);
  conv_fix<<<3136, 256, 0, stream>>>(convAcc, conv_b, qeb);
  gemm_kernel<0, KQ, 5><<<dim3(256, 2), 256, 0, stream>>>(qeb, hp_w0t, biasHP, hp_w1, att, nullptr);
  sel_kernel<<<128, 256, 0, stream>>>(att, qeb, gt_w0, biasGT, bias2);
  gemm_kernel<1, KQ, 5><<<dim3(256, 2), 256, 0, stream>>>(qeb, gt_w0t, bias2, nullptr, nullptr, g1);
  gemm_kernel<2, 256, 8><<<dim3(256, 2), 256, 0, stream>>>(g1, gt_w1t, gt_b1, nullptr, relations, nullptr);
  fphi<<<128, 256, 0, stream>>>(relations, fp_w0, fp_b0, fp_w1, fp_b1, out);
}

// Round 7
// 366.846 us; speedup vs baseline: 1.1827x; 1.0408x over previous
//
#include <hip/hip_runtime.h>
#include <stdint.h>

typedef unsigned short u16;
typedef __bf16 bf16x8 __attribute__((ext_vector_type(8)));
typedef float f32x4 __attribute__((ext_vector_type(4)));

// ---------- helpers ----------
__device__ __forceinline__ u16 f2b(float f) {
  union { float f; uint32_t u; } v; v.f = f;
  uint32_t r = v.u + 0x7fffu + ((v.u >> 16) & 1u);
  return (u16)(r >> 16);
}
__device__ __forceinline__ float b2f(u16 b) {
  union { float f; uint32_t u; } v; v.u = ((uint32_t)b) << 16;
  return v.f;
}
// async 16B/lane global->LDS (dest = uniform base + lane*16)
__device__ __forceinline__ void g2l16(const void* g, void* l) {
  __builtin_amdgcn_global_load_lds(
      (const __attribute__((address_space(1))) void*)g,
      (__attribute__((address_space(3))) void*)l, 16, 0, 0);
}

#define N_SAMP 128
#define OPAD   224
#define ROWS   (N_SAMP * OPAD)   // 28672
#define KQ     160               // qeb K: 128 conv + 2 coords + 30 zero pad

// ---------- K0: fused prep (W2 repack | image transpose | misc init) ----------
// Block ranges: [0,512) prep_w2 | [512,2560) prep_img | [2560,8380) init ranges.
#define R_HP   40960      // hp_w0t 256*160
#define R_GT0  40960      // gt_w0t 256*160
#define R_GT1  65536      // gt_w1t 256*256
#define R_BHP  32768      // biasHP 128*256 (128-iter loop)
#define R_BGT  32768      // biasGT 128*256 (128-iter loop)
#define R_QC   (ROWS * 8) // qeb coord quads (cols 128..159)
#define R_QP   114688     // qeb pad rows: 3584 rows x 32 quads (cols 0..127)
#define R_ATT  7168       // att zero, float4
#define R_REL  8192       // relations zero, float4
#define R_CVA  917504     // convAcc zero, float4
// init total 1,489,920 = 5820 * 256; grid = 512 + 2048 + 5820 = 8380
__global__ __launch_bounds__(256) void prep_all(
    const float* __restrict__ conv_w, const float* __restrict__ image,
    const float* __restrict__ hp_w0, const float* __restrict__ gt_w0,
    const float* __restrict__ gt_w1, const float* __restrict__ hp_b0,
    const float* __restrict__ gt_b0, const float* __restrict__ code,
    u16* __restrict__ W2, u16* __restrict__ imgT,
    u16* __restrict__ hp_w0t, u16* __restrict__ gt_w0t, u16* __restrict__ gt_w1t,
    float* __restrict__ biasHP, float* __restrict__ biasGT, u16* __restrict__ qeb,
    float* __restrict__ att, float* __restrict__ relations,
    float* __restrict__ convAcc) {
  __shared__ float ls[64 * 197];   // 50.4 KB union: prep_w2 uses first 2304 floats
  int bid = blockIdx.x;
  int t = threadIdx.x;

  if (bid < 512) {
    // --- W2 repack via LDS transpose (coalesced conv_w read) ---
    int p0 = bid << 8;
    const float* src = conv_w + (size_t)p0 * 9;
#pragma unroll
    for (int i = 0; i < 9; ++i) ls[t + i * 256] = src[t + i * 256];
    __syncthreads();
#pragma unroll
    for (int s = 0; s < 9; ++s)
      W2[s * 131072 + p0 + t] = f2b(ls[t * 9 + s]);   // 9 coprime 32 -> conflict-free
    return;
  }
  bid -= 512;

  if (bid < 2048) {
    // --- image -> imgT[n][256 sp (16x16 zero-bordered)][1024 cin] bf16, 16B/lane writes ---
    float (*tt)[197] = (float(*)[197])ls;
    int n = bid >> 4;
    int cin0 = (bid & 15) * 64;
    const float* src = image + ((size_t)n * 1024 + cin0) * 196;
    for (int e = t; e < 64 * 196; e += 256) {
      int c = e / 196, sp = e % 196;
      tt[c][sp] = src[c * 196 + sp];
    }
    __syncthreads();
#pragma unroll
    for (int i = 0; i < 8; ++i) {
      int qid = t + i * 256;     // 2048 chunks of 8 bf16
      int spg = qid >> 3, qd = qid & 7;
      int gy = spg >> 4, gx = spg & 15;
      uint4 pk = {0u, 0u, 0u, 0u};
      if (gy >= 1 && gy <= 14 && gx >= 1 && gx <= 14) {
        int sp = (gy - 1) * 14 + (gx - 1);
        uint32_t vv[8];
#pragma unroll
        for (int j = 0; j < 8; ++j) vv[j] = f2b(tt[qd * 8 + j][sp]);
        pk.x = vv[0] | (vv[1] << 16);
        pk.y = vv[2] | (vv[3] << 16);
        pk.z = vv[4] | (vv[5] << 16);
        pk.w = vv[6] | (vv[7] << 16);
      }
      *(uint4*)(imgT + (((size_t)(n * 256 + spg)) << 10) + cin0 + qd * 8) = pk;
    }
    return;
  }
  bid -= 2048;

  // --- misc init ranges ---
  int idx = bid * 256 + t;
  if (idx < R_HP) {
    int nn = idx / KQ, kk = idx % KQ;
    hp_w0t[idx] = (kk < 130) ? f2b(hp_w0[kk * 256 + nn]) : (u16)0;
    return;
  }
  idx -= R_HP;
  if (idx < R_GT0) {
    int nn = idx / KQ, kk = idx % KQ;
    gt_w0t[idx] = (kk < 130) ? f2b(gt_w0[kk * 256 + nn]) : (u16)0;
    return;
  }
  idx -= R_GT0;
  if (idx < R_GT1) {
    int nn = idx >> 8, kk = idx & 255;
    gt_w1t[idx] = f2b(gt_w1[kk * 256 + nn]);
    return;
  }
  idx -= R_GT1;
  if (idx < R_BHP) {
    int n = idx >> 8, tc = idx & 255;
    float acc = hp_b0[tc];
    for (int d = 0; d < 128; ++d) acc += code[n * 128 + d] * hp_w0[(130 + d) * 256 + tc];
    biasHP[idx] = acc;
    return;
  }
  idx -= R_BHP;
  if (idx < R_BGT) {
    int n = idx >> 8, tc = idx & 255;
    float acc = gt_b0[tc];
    for (int d = 0; d < 128; ++d) acc += code[n * 128 + d] * gt_w0[(130 + d) * 256 + tc];
    biasGT[idx] = acc;
    return;
  }
  idx -= R_BGT;
  if (idx < R_QC) {
    int row = idx >> 3, qd = idx & 7;
    int o = row % 224;
    ushort4 v = {0, 0, 0, 0};
    if (o < 196 && qd == 0) {
      int y = o / 14, x = o % 14;
      v.x = f2b(-1.f + 2.f * y / 13.f);
      v.y = f2b(-1.f + 2.f * x / 13.f);
    }
    *(ushort4*)(qeb + (size_t)row * KQ + 128 + qd * 4) = v;
    return;
  }
  idx -= R_QC;
  if (idx < R_QP) {
    int pr = idx >> 5, qd = idx & 31;
    int row = (pr / 28) * 224 + 196 + (pr % 28);
    *(ushort4*)(qeb + (size_t)row * KQ + qd * 4) = (ushort4){0, 0, 0, 0};
    return;
  }
  idx -= R_QP;
  if (idx < R_ATT) { *((float4*)att + idx) = (float4){0.f, 0.f, 0.f, 0.f}; return; }
  idx -= R_ATT;
  if (idx < R_REL) { *((float4*)relations + idx) = (float4){0.f, 0.f, 0.f, 0.f}; return; }
  idx -= R_REL;
  *((float4*)convAcc + idx) = (float4){0.f, 0.f, 0.f, 0.f};
}

// ---------- K1: conv as implicit GEMM, split-K x3 (round-0 proven structure) ----------
// grid 768 = 8 xcd * (16 ngrp * 2 ohalf * 3 kslice); BK=64; swizzled LDS.
__global__ __launch_bounds__(256) void conv_gemm(
    const u16* __restrict__ imgT, const u16* __restrict__ W2,
    float* __restrict__ convAcc) {
  __shared__ __align__(16) u16 lA[112 * 64];
  __shared__ __align__(16) u16 lB[128 * 64];
  int tid = threadIdx.x, lane = tid & 63, w = tid >> 6;
  int wg = blockIdx.x;
  int xcd = wg & 7, grp = wg >> 3;          // same-n blocks land on same XCD
  int n = ((grp / 6) << 3) | xcd;
  int r6 = grp % 6;
  int oh = r6 / 3, ks = r6 % 3;
  int oBase = oh * 112;
  size_t nBase = (size_t)n << 8;
  int rowIn = lane >> 3;                    // row within 8-row staging instr
  int cA = ((lane & 7) ^ rowIn) << 3;       // XOR-swizzled chunk offset (elems)

  // A-row spatial precompute for staging instrs t = w + 4*ii
  int yxA[4];
  for (int ii = 0; ii < 4; ++ii) {
    int t = w + ii * 4;
    int o = oBase + t * 8 + rowIn;
    bool valid = o < 196;
    int y = o / 14, x = o - y * 14;
    yxA[ii] = valid ? (y * 16 + x) : 0;    // invalid rows read border zeros / garbage; outputs discarded
  }

  f32x4 acc[7][2];
#pragma unroll
  for (int mt = 0; mt < 7; ++mt)
#pragma unroll
    for (int j = 0; j < 2; ++j) acc[mt][j] = (f32x4){0.f, 0.f, 0.f, 0.f};

  int l = lane & 15, q = lane >> 4;
  for (int si = 0; si < 3; ++si) {
    int s = ks * 3 + si;
    int off = (s / 3) * 16 + (s % 3);
    const u16* Ws = W2 + ((size_t)(s * 128) << 10);
    for (int cb = 0; cb < 16; ++cb) {
      int k0 = cb << 6;
      __syncthreads();
      // stage A: 14 instrs (waves 0,1: 4 each; waves 2,3: 3 each)
      g2l16(imgT + ((nBase + (size_t)(yxA[0] + off)) << 10) + k0 + cA, &lA[(w) * 512]);
      g2l16(imgT + ((nBase + (size_t)(yxA[1] + off)) << 10) + k0 + cA, &lA[(w + 4) * 512]);
      g2l16(imgT + ((nBase + (size_t)(yxA[2] + off)) << 10) + k0 + cA, &lA[(w + 8) * 512]);
      if (w < 2)
        g2l16(imgT + ((nBase + (size_t)(yxA[3] + off)) << 10) + k0 + cA, &lA[(w + 12) * 512]);
      // stage B: 16 instrs (4 per wave)
#pragma unroll
      for (int ii = 0; ii < 4; ++ii) {
        int t = w + ii * 4;
        g2l16(Ws + ((size_t)(t * 8 + rowIn) << 10) + k0 + cA, &lB[t * 512]);
      }
      __syncthreads();
#pragma unroll
      for (int kk = 0; kk < 2; ++kk) {
        int co = ((((kk << 2) | q) ^ (l & 7)) << 3);
        bf16x8 af[7];
#pragma unroll
        for (int mt = 0; mt < 7; ++mt)
          af[mt] = *(const bf16x8*)&lA[(mt * 16 + l) * 64 + co];
#pragma unroll
        for (int jj = 0; jj < 2; ++jj) {
          bf16x8 bb = *(const bf16x8*)&lB[(w * 32 + jj * 16 + l) * 64 + co];
#pragma unroll
          for (int mt = 0; mt < 7; ++mt)
            acc[mt][jj] = __builtin_amdgcn_mfma_f32_16x16x32_bf16(af[mt], bb, acc[mt][jj], 0, 0, 0);
        }
      }
    }
  }
  // epilogue: atomic fp32 accumulate of the K-slice partial
#pragma unroll
  for (int mt = 0; mt < 7; ++mt) {
    int o = oBase + mt * 16 + q * 4;
#pragma unroll
    for (int r4 = 0; r4 < 4; ++r4) {
      if (o + r4 < 196) {
        float* dst = convAcc + (size_t)(n * 224 + o + r4) * 128 + w * 32 + l;
        atomicAdd(dst, acc[mt][0][r4]);
        atomicAdd(dst + 16, acc[mt][1][r4]);
      }
    }
  }
}

// ---------- K1b: convAcc + bias -> qeb bf16 cols 0..127 ----------
__global__ __launch_bounds__(256) void conv_fix(
    const float* __restrict__ convAcc, const float* __restrict__ conv_b,
    u16* __restrict__ qeb) {
  int idx = blockIdx.x * 256 + threadIdx.x;   // 128*196*32
  int row196 = idx >> 5;
  int c0 = (idx & 31) << 2;
  int n = row196 / 196, o = row196 - n * 196;
  size_t row = (size_t)(n * 224 + o);
  const float4 v = *(const float4*)(convAcc + (row << 7) + c0);
  const float4 b = *(const float4*)(conv_b + c0);
  ushort4 pk;
  pk.x = f2b(v.x + b.x); pk.y = f2b(v.y + b.y);
  pk.z = f2b(v.z + b.z); pk.w = f2b(v.w + b.w);
  *(ushort4*)(qeb + row * KQ + c0) = pk;
}

// ---------- generic GEMM skeleton: C[28672, 256] = A[28672,KP]bf16 * Bt[256,KP]^T ----------
// Double-buffered counted-vmcnt pipeline; 4 global_load_lds per wave per K-step.
// A staging padded to 128 rows (row group 7 garbage, never read by MFMA).
// MODE 0: bias per-n (biasHP incl. code part). MODE 1: per-n bias2.
template <int MODE, int KP, int KC>
__global__ __launch_bounds__(256) void gemm_kernel(
    const u16* __restrict__ A, const u16* __restrict__ Bt,
    const float* __restrict__ bias, const float* __restrict__ vec,
    float* __restrict__ outF, u16* __restrict__ outB) {
  __shared__ __align__(16) u16 lA[2][128 * 32];
  __shared__ __align__(16) u16 lB[2][128 * 32];
  int tid = threadIdx.x, lane = tid & 63, w = tid >> 6;
  int bx = blockIdx.x, by = blockIdx.y;
  int r0 = bx * 112;
  int cBase = by * 128;
  int kb = (((lane & 3) ^ ((lane >> 3) & 3)) << 3);   // XOR-swizzled source chunk
  int rA0 = r0 + w * 16 + (lane >> 2);
  int rA1 = r0 + (w + 4) * 16 + (lane >> 2);          // group 7 (rows 112..127) = pad
  const u16* gA0 = A + (size_t)rA0 * KP + kb;
  const u16* gA1 = A + (size_t)rA1 * KP + kb;
  int cB0 = cBase + w * 16 + (lane >> 2);
  int cB1 = cBase + (w + 4) * 16 + (lane >> 2);
  const u16* gB0 = Bt + (size_t)cB0 * KP + kb;
  const u16* gB1 = Bt + (size_t)cB1 * KP + kb;

  f32x4 acc[7][2];
#pragma unroll
  for (int mt = 0; mt < 7; ++mt)
#pragma unroll
    for (int j = 0; j < 2; ++j) acc[mt][j] = (f32x4){0.f, 0.f, 0.f, 0.f};
  int colW = w * 32;
  int l = lane & 15, q = lane >> 4;
  int co = ((q ^ ((l >> 1) & 3)) << 3);

  auto STAGE = [&](int buf, int cb) {
    g2l16(gA0 + cb * 32, &lA[buf][w * 512]);
    g2l16(gA1 + cb * 32, &lA[buf][(w + 4) * 512]);
    g2l16(gB0 + cb * 32, &lB[buf][w * 512]);
    g2l16(gB1 + cb * 32, &lB[buf][(w + 4) * 512]);
  };

  auto COMPUTE = [&](int cur) {
    bf16x8 af[7];
#pragma unroll
    for (int mt = 0; mt < 7; ++mt)
      af[mt] = *(const bf16x8*)&lA[cur][(mt * 16 + l) * 32 + co];
#pragma unroll
    for (int j = 0; j < 2; ++j) {
      bf16x8 bfr = *(const bf16x8*)&lB[cur][(colW + j * 16 + l) * 32 + co];
#pragma unroll
      for (int mt = 0; mt < 7; ++mt)
        acc[mt][j] = __builtin_amdgcn_mfma_f32_16x16x32_bf16(af[mt], bfr, acc[mt][j], 0, 0, 0);
    }
  };

  STAGE(0, 0);
#pragma unroll
  for (int it = 0; it < KC - 1; ++it) {
    STAGE((it & 1) ^ 1, it + 1);
    asm volatile("s_waitcnt vmcnt(4)" ::: "memory");   // prev step's 4 loads done; 4 in flight
    __builtin_amdgcn_s_barrier();
    __builtin_amdgcn_sched_barrier(0);
    COMPUTE(it & 1);
    __builtin_amdgcn_s_barrier();                      // all reads done before next STAGE overwrites
    __builtin_amdgcn_sched_barrier(0);
  }
  asm volatile("s_waitcnt vmcnt(0)" ::: "memory");
  __builtin_amdgcn_s_barrier();
  __builtin_amdgcn_sched_barrier(0);
  COMPUTE((KC - 1) & 1);

  int q4 = lane >> 4, c = lane & 15;
  if (MODE == 0) {
    int n = bx >> 1;
    float attp[7][4];
#pragma unroll
    for (int mt = 0; mt < 7; ++mt)
#pragma unroll
      for (int r = 0; r < 4; ++r) attp[mt][r] = 0.f;
#pragma unroll
    for (int j = 0; j < 2; ++j) {
      int col = cBase + colW + j * 16 + c;
      float b0 = bias[n * 256 + col], w1 = vec[col];
#pragma unroll
      for (int mt = 0; mt < 7; ++mt)
#pragma unroll
        for (int r = 0; r < 4; ++r) {
          float v = fmaxf(acc[mt][j][r] + b0, 0.f);
          attp[mt][r] += v * w1;
        }
    }
#pragma unroll
    for (int mt = 0; mt < 7; ++mt)
#pragma unroll
      for (int r = 0; r < 4; ++r) {
        float p = attp[mt][r];
        p += __shfl_xor(p, 1, 64);
        p += __shfl_xor(p, 2, 64);
        p += __shfl_xor(p, 4, 64);
        p += __shfl_xor(p, 8, 64);
        if (c == 0) atomicAdd(&outF[r0 + mt * 16 + q4 * 4 + r], p);
      }
  } else if (MODE == 1) {
    int n = bx >> 1;
#pragma unroll
    for (int mt = 0; mt < 7; ++mt)
#pragma unroll
      for (int j = 0; j < 2; ++j) {
        int col = cBase + colW + j * 16 + c;
        float b = bias[n * 256 + col];
#pragma unroll
        for (int r = 0; r < 4; ++r) {
          int row = r0 + mt * 16 + q4 * 4 + r;
          outB[(size_t)row * 256 + col] = f2b(fmaxf(acc[mt][j][r] + b, 0.f));
        }
      }
  } else {
    int n = bx >> 1;
    int ob = (bx & 1) * 112;
#pragma unroll
    for (int j = 0; j < 2; ++j) {
      int col = cBase + colW + j * 16 + c;
      float b = bias[col];
      float sum = 0.f;
#pragma unroll
      for (int mt = 0; mt < 7; ++mt)
#pragma unroll
        for (int r = 0; r < 4; ++r) {
          int o = ob + mt * 16 + q4 * 4 + r;
          if (o < 196) sum += fmaxf(acc[mt][j][r] + b, 0.f);
        }
      sum += __shfl_xor(sum, 16, 64);
      sum += __shfl_xor(sum, 32, 64);
      if (q4 == 0) atomicAdd(&outF[n * 256 + col], sum);
    }
  }
}

// ---------- K5: softmax over objects, soft-select, per-n bias2 (code part precomputed) ----------
__global__ __launch_bounds__(256) void sel_kernel(
    const float* __restrict__ att, const u16* __restrict__ qeb,
    const float* __restrict__ gt_w0, const float* __restrict__ biasGT,
    float* __restrict__ bias2) {
  int n = blockIdx.x, t = threadIdx.x;
  int w = t >> 6, lane = t & 63;
  __shared__ u16 sq[196][130];
  __shared__ float sm[196];
  __shared__ float sel[130];
  __shared__ float red[8];
  // cooperative stage of qeb[n, 0:196, 0:130]
  const u16* base = qeb + (size_t)n * 224 * KQ;
  for (int o = w; o < 196; o += 4) {
    const u16* rowp = base + (size_t)o * KQ;
    for (int c = lane; c < 130; c += 64) sq[o][c] = rowp[c];
  }
  float a = (t < 196) ? att[n * 224 + t] : -1e30f;
  float m = a;
  for (int mask = 1; mask < 64; mask <<= 1) m = fmaxf(m, __shfl_xor(m, mask, 64));
  if (lane == 0) red[w] = m;
  __syncthreads();
  float M = fmaxf(fmaxf(red[0], red[1]), fmaxf(red[2], red[3]));
  float e = (t < 196) ? expf(a - M) : 0.f;
  float sAcc = e;
  for (int mask = 1; mask < 64; mask <<= 1) sAcc += __shfl_xor(sAcc, mask, 64);
  if (lane == 0) red[4 + w] = sAcc;
  __syncthreads();
  float S = red[4] + red[5] + red[6] + red[7];
  if (t < 196) sm[t] = e / S;
  __syncthreads();
  if (t < 130) {
    float acc = 0.f;
    for (int o = 0; o < 196; ++o) acc += sm[o] * b2f(sq[o][t]);
    sel[t] = acc;
  }
  __syncthreads();
  float acc2 = biasGT[n * 256 + t];
  for (int d = 0; d < 130; ++d) acc2 += sel[d] * gt_w0[(258 + d) * 256 + t];
  bias2[n * 256 + t] = acc2;
}

// ---------- K8: f_phi ----------
__global__ __launch_bounds__(256) void fphi(
    const float* __restrict__ relations, const float* __restrict__ fp_w0,
    const float* __restrict__ fp_b0, const float* __restrict__ fp_w1,
    const float* __restrict__ fp_b1, float* __restrict__ out) {
  int n = blockIdx.x, t = threadIdx.x;
  __shared__ float rel[256];
  __shared__ float f[256];
  rel[t] = relations[n * 256 + t];
  __syncthreads();
  float acc = fp_b0[t];
  for (int k = 0; k < 256; ++k) acc += rel[k] * fp_w0[k * 256 + t];
  f[t] = fmaxf(acc, 0.f);
  __syncthreads();
  if (t < 32) {
    float o = fp_b1[0];
    for (int k = 0; k < 256; ++k) o += f[k] * fp_w1[k * 32 + t];
    out[n * 32 + t] = o;
  }
}

extern "C" void kernel_launch(void* const* d_in, const int* in_sizes, int n_in,
                              void* d_out, int out_size, void* d_ws, size_t ws_size,
                              hipStream_t stream) {
  const float* image = (const float*)d_in[0];
  const float* code = (const float*)d_in[1];
  const float* conv_w = (const float*)d_in[2];
  const float* conv_b = (const float*)d_in[3];
  const float* hp_w0 = (const float*)d_in[4];
  const float* hp_b0 = (const float*)d_in[5];
  const float* hp_w1 = (const float*)d_in[6];
  /* hp_b1: softmax shift-invariant, dropped */
  const float* gt_w0 = (const float*)d_in[8];
  const float* gt_b0 = (const float*)d_in[9];
  const float* gt_w1 = (const float*)d_in[10];
  const float* gt_b1 = (const float*)d_in[11];
  const float* fp_w0 = (const float*)d_in[12];
  const float* fp_b0 = (const float*)d_in[13];
  const float* fp_w1 = (const float*)d_in[14];
  const float* fp_b1 = (const float*)d_in[15];
  float* out = (float*)d_out;

  char* p = (char*)d_ws;
  u16* imgT = (u16*)p;   p += (size_t)128 * 256 * 1024 * 2;   // 67.1 MB
  u16* W2 = (u16*)p;     p += (size_t)9 * 128 * 1024 * 2;     // 2.36 MB
  u16* qeb = (u16*)p;    p += (size_t)ROWS * KQ * 2;          // 9.2 MB
  u16* hp_w0t = (u16*)p; p += (size_t)256 * KQ * 2;
  u16* gt_w0t = (u16*)p; p += (size_t)256 * KQ * 2;
  u16* gt_w1t = (u16*)p; p += (size_t)256 * 256 * 2;
  float* att = (float*)p;    p += (size_t)ROWS * 4;
  float* bias2 = (float*)p;  p += (size_t)128 * 256 * 4;
  float* biasHP = (float*)p; p += (size_t)128 * 256 * 4;
  float* biasGT = (float*)p; p += (size_t)128 * 256 * 4;
  float* convAcc = (float*)p; p += (size_t)ROWS * 128 * 4;    // 14.7 MB; reused as g1
  float* relations = (float*)p; p += (size_t)128 * 256 * 4;
  u16* g1 = (u16*)convAcc;   // alias: convAcc dead after conv_fix, g1 born at MODE1

  prep_all<<<8380, 256, 0, stream>>>(conv_w, image, hp_w0, gt_w0, gt_w1, hp_b0, gt_b0,
                                     code, W2, imgT, hp_w0t, gt_w0t, gt_w1t,
                                     biasHP, biasGT, qeb, att, relations, convAcc);
  conv_gemm<<<768, 256, 0, stream>>>(imgT, W2, convAcc);
  conv_fix<<<3136, 256, 0, stream>>>(convAcc, conv_b, qeb);
  gemm_kernel<0, KQ, 5><<<dim3(256, 2), 256, 0, stream>>>(qeb, hp_w0t, biasHP, hp_w1, att, nullptr);
  sel_kernel<<<128, 256, 0, stream>>>(att, qeb, gt_w0, biasGT, bias2);
  gemm_kernel<1, KQ, 5><<<dim3(256, 2), 256, 0, stream>>>(qeb, gt_w0t, bias2, nullptr, nullptr, g1);
  gemm_kernel<2, 256, 8><<<dim3(256, 2), 256, 0, stream>>>(g1, gt_w1t, gt_b1, nullptr, relations, nullptr);
  fphi<<<128, 256, 0, stream>>>(relations, fp_w0, fp_b0, fp_w1, fp_b1, out);
}